// Round 10
// baseline (475.874 us; speedup 1.0000x reference)
//
#include <hip/hip_runtime.h>
#include <hip/hip_bf16.h>
#include <math.h>
#include <stdint.h>

// Problem constants (reference: B=4, T=2048, C=1024, H=16, HD=64)
#define BB 4
#define TT 2048
#define CC 1024
#define HH 16
#define HD 64
#define MM (BB*TT)   // 8192
#define NQT2 16      // T / 128 q-tiles for attention (QBLK=128)
#define SCQ 0.180336878f   // (1/sqrt(HD)) * log2(e): Q pre-scale for exp2-domain softmax

using f32x2  = __attribute__((ext_vector_type(2))) float;
using f32x4  = __attribute__((ext_vector_type(4))) float;
using f32x16 = __attribute__((ext_vector_type(16))) float;
using i32x4  = __attribute__((ext_vector_type(4))) int;
using bf16x4 = __attribute__((ext_vector_type(4))) __bf16;
using bf16x8 = __attribute__((ext_vector_type(8))) __bf16;

__device__ __forceinline__ float fast_exp2(float x) {
  return __builtin_amdgcn_exp2f(x);   // v_exp_f32 (native exp2 on gfx950)
}

__device__ __forceinline__ int cvt_pk_bf16(float lo, float hi_) {
  int r;
  asm("v_cvt_pk_bf16_f32 %0, %1, %2" : "=v"(r) : "v"(lo), "v"(hi_));
  return r;   // low 16 = bf16(lo), high 16 = bf16(hi_)
}

__device__ __forceinline__ f32x2 max2(f32x2 a, f32x2 b) {
  return __builtin_elementwise_max(a, b);   // v_pk_max_f32
}

__device__ __forceinline__ void gload_lds16(const void* g, void* l) {
  __builtin_amdgcn_global_load_lds(
      (__attribute__((address_space(1))) void*)(void*)(g),
      (__attribute__((address_space(3))) void*)(l), 16, 0, 0);
}

// ---------------- fp32 -> bf16 converts ----------------
__global__ __launch_bounds__(256)
void cvt_f32_bf16(const float* __restrict__ s, __bf16* __restrict__ d, int n4) {
  int i = blockIdx.x * 256 + threadIdx.x;
  if (i >= n4) return;
  float4 v = ((const float4*)s)[i];
  bf16x4 o;
  o[0] = (__bf16)v.x; o[1] = (__bf16)v.y; o[2] = (__bf16)v.z; o[3] = (__bf16)v.w;
  *(bf16x4*)(d + (size_t)i * 4) = o;
}

// 4 weights in one launch; Wq scaled by SCQ and Wq/Wk/Wv written into the
// contiguous [3072][1024] concat buffer (order q,k,v); Wp separate.
__global__ __launch_bounds__(256)
void cvt_w4(const float* __restrict__ Wq, const float* __restrict__ Wk,
            const float* __restrict__ Wv, const float* __restrict__ Wp,
            __bf16* __restrict__ wqkv, __bf16* __restrict__ wpb) {
  int which = blockIdx.y;
  const float* s = which == 0 ? Wq : which == 1 ? Wk : which == 2 ? Wv : Wp;
  __bf16* d = which == 3 ? wpb : wqkv + (size_t)which * CC * CC;
  float sc = which == 0 ? SCQ : 1.f;
  int i = blockIdx.x * 256 + threadIdx.x;   // grid.x = (CC*CC/4)/256 = 1024
  float4 v = ((const float4*)s)[i];
  bf16x4 o;
  o[0] = (__bf16)(v.x * sc); o[1] = (__bf16)(v.y * sc);
  o[2] = (__bf16)(v.z * sc); o[3] = (__bf16)(v.w * sc);
  *(bf16x4*)(d + (size_t)i * 4) = o;
}

#define WAITV0 asm volatile("s_waitcnt vmcnt(0)" ::: "memory")
#define SB0    __builtin_amdgcn_sched_barrier(0)

// ======= QKV GEMM v10: 256x128 tile, 8 waves, 3 blocks/CU co-resident =======
// C[8192,3072] = A[8192,1024] x Wqkv[3072,1024]^T + bias.
// r9 post-mortem synthesis:
//  * grid 32x24 = 768 = EXACTLY 3.0 blocks/CU, all co-resident (LDS 33.8KB,
//    launch_bounds(512,6) caps VGPR at 85; r9's identical core was 60).
//  * 24 waves/CU (vs r9's 16 / 8-phase's 8): cross-block TLP fills the
//    staging/barrier stalls the 1-block lockstep couldn't.
//  * conflict-free fragment reads: r9's [row][64B] pattern was 8 lanes/bank-
//    span (6.4M conflict cycles). Slot-swizzle slot=(g+(lq>>1))&3 spreads all
//    8 spans exactly twice per 16-lane group (2/bank = free). Applied both-
//    sides (rule 21): linear LDS dest, inverse-swizzled global src col.
//  * per-wave shape = m97's validated 64x64 (4x4 acc of 16x16x32).
// Waves: 4M x 2N (wm=wid>>1 -> 64 rows, wn=wid&1 -> 64 of 128 cols).
// proj 0/1 (Q,K): bf16 head-split store; proj 2 (V): 2x 64-col LDS transpose
// chunks (lt aliases As/Bs, barrier-protected) -> Vt[bh][d][t].
__global__ __launch_bounds__(512, 6)
void gemm_qkv(const __bf16* __restrict__ A, const __bf16* __restrict__ Bm,
              const float* __restrict__ b0, const float* __restrict__ b1,
              const float* __restrict__ b2, __bf16* __restrict__ out,
              __bf16* __restrict__ vt) {
  __shared__ __bf16 U[16896];          // 33.8KB = As[8192] + Bs[4096]; lt alias
  __bf16* As = U;                      // [256][32]
  __bf16* Bs = U + 8192;               // [128][32]
  const int tid = threadIdx.x, wid = tid >> 6, lane = tid & 63;
  const int g = lane >> 4, lq = lane & 15;
  const int wm = wid >> 1, wn = wid & 1;   // 4M x 2N waves, 64x64 each
  // XCD-chunk swizzle: 768 blocks = 8 XCDs x 96 contiguous logicals
  const int bx0 = blockIdx.x;
  const int bx = (bx0 & 7) * 96 + (bx0 >> 3);
  const int bm = bx / 24, bn = bx % 24;
  const int brow = bm << 8, bcol = bn << 7;

  // staging chunk geometry: chunk c -> row c>>2, slot c&3; the global source
  // column chunk is inverse-swizzled so that the READ-side swizzle
  // slot=(g+(row>>1))&3 recovers K-chunk g.
  const int ca = tid, cb = tid + 512;
  const int ra = ca >> 2, sa_ = (((ca & 3) - (ra >> 1)) & 3) << 4;
  const int rb = cb >> 2, sb_ = (((cb & 3) - (rb >> 1)) & 3) << 4;

  f32x4 acc[4][4] = {};

  for (int kt = 0; kt < CC; kt += 32) {
    __syncthreads();
    gload_lds16((const char*)A + (size_t)(brow + ra) * 2048 + kt * 2 + sa_,
                (char*)As + ca * 16);
    gload_lds16((const char*)A + (size_t)(brow + rb) * 2048 + kt * 2 + sb_,
                (char*)As + cb * 16);
    gload_lds16((const char*)Bm + (size_t)(bcol + ra) * 2048 + kt * 2 + sa_,
                (char*)Bs + ca * 16);
    __syncthreads();
    bf16x8 av[4], bv[4];
#pragma unroll
    for (int m = 0; m < 4; ++m) {
      int row = wm * 64 + m * 16 + lq;
      int sl = (g + (row >> 1)) & 3;
      av[m] = *(const bf16x8*)((const char*)As + row * 64 + sl * 16);
    }
#pragma unroll
    for (int n = 0; n < 4; ++n) {
      int row = wn * 64 + n * 16 + lq;
      int sl = (g + (row >> 1)) & 3;
      bv[n] = *(const bf16x8*)((const char*)Bs + row * 64 + sl * 16);
    }
#pragma unroll
    for (int m = 0; m < 4; ++m)
#pragma unroll
      for (int n = 0; n < 4; ++n)
        acc[m][n] = __builtin_amdgcn_mfma_f32_16x16x32_bf16(av[m], bv[n], acc[m][n], 0, 0, 0);
  }

  const int proj = bn >> 3;   // uniform per block (8 x 128 = 1024 cols / proj)
  if (proj < 2) {
    // epilogue: bias + bf16 head-split store [proj][B,H,T,HD]
    const float* bias = proj == 0 ? b0 : b1;
    const float bsc = proj == 0 ? SCQ : 1.f;
#pragma unroll
    for (int n = 0; n < 4; ++n) {
      int col = bcol + wn * 64 + n * 16 + lq;
      int cw = col & (CC - 1);
      float bb = bias[cw] * bsc;
      int h_ = cw >> 6, d_ = cw & (HD - 1);
#pragma unroll
      for (int m = 0; m < 4; ++m) {
        int row0 = brow + wm * 64 + m * 16 + g * 4;
#pragma unroll
        for (int i = 0; i < 4; ++i) {
          int row = row0 + i;
          int b_ = row >> 11, t_ = row & (TT - 1);
          out[((size_t)proj << 23) +
              ((((size_t)b_ * HH + h_) * TT + t_) << 6) + d_] =
              (__bf16)(acc[m][n][i] + bb);
        }
      }
    }
  } else {
    // V: transpose 256x128 tile through lt (2 chunks of 64 cols = 1 head
    // each) and write Vt[bh][d][t] coalesced. lt aliases As/Bs.
    __syncthreads();                             // all K-loop LDS reads done
    __bf16* lt = U;                              // [64 cols][264 rows]
    const int cv0 = (bn & 7) << 7;               // col offset within V region
    const int b_ = brow >> 11, t0 = brow & (TT - 1);
    const int hbase = (bn & 7) << 1;
    const int rd_d = tid >> 3, rd_tb = (tid & 7) << 5;   // 64 d x 256 t
#pragma unroll
    for (int cc = 0; cc < 2; ++cc) {
      if (wn == cc) {                            // 4 writer waves (all wm)
#pragma unroll
        for (int n = 0; n < 4; ++n) {
          int c = (n << 4) + lq;                 // 0..63 within chunk
          float bb = b2[cv0 + (cc << 6) + c];
#pragma unroll
          for (int m = 0; m < 4; ++m) {
            int r = wm * 64 + (m << 4) + (g << 2);   // 0..255
            bf16x4 pk;
#pragma unroll
            for (int i = 0; i < 4; ++i)
              pk[i] = (__bf16)(acc[m][n][i] + bb);
            *(bf16x4*)(lt + c * 264 + r) = pk;
          }
        }
      }
      __syncthreads();
      // readers: all 512 threads; d = tid>>3, 32 t-elems each
      __bf16* dst = vt + (((size_t)((b_ * HH + hbase + cc) * HD + rd_d)) << 11)
                       + t0 + rd_tb;
      const __bf16* srcl = lt + rd_d * 264 + rd_tb;
#pragma unroll
      for (int j = 0; j < 4; ++j)
        *(bf16x8*)(dst + j * 8) = *(const bf16x8*)(srcl + j * 8);
      __syncthreads();
    }
  }
}

// ---------------- proj GEMM (m97 structure): fp32 out ----------------
__global__ __launch_bounds__(256, 2)
void gemm_proj(const __bf16* __restrict__ A, const __bf16* __restrict__ Bm,
               const float* __restrict__ bias, float* __restrict__ out,
               int M, int N, int K) {
  __shared__ __bf16 As[128 * 32];
  __shared__ __bf16 Bs[128 * 32];
  const int tid = threadIdx.x;
  const int wid = tid >> 6, lane = tid & 63;
  const int g = lane >> 4, lq = lane & 15;
  const int nbn = N >> 7;
  // XCD-chunk swizzle (bijective when gridDim.x % 8 == 0; our launch: 512)
  int bx = blockIdx.x;
  const int nb = gridDim.x;
  if ((nb & 7) == 0) { const int q = nb >> 3; bx = (bx & 7) * q + (bx >> 3); }
  const int brow = (bx / nbn) << 7;
  const int bcol = (bx % nbn) << 7;
  const int wr = (wid >> 1) << 6, wc = (wid & 1) << 6;

  f32x4 acc[4][4] = {};

  const int o0 = wid * 2048 + lane * 16;
  for (int kt = 0; kt < K; kt += 32) {
    __syncthreads();
#pragma unroll
    for (int j = 0; j < 2; ++j) {
      int o = o0 + j * 1024;
      int row = o >> 6, colb = o & 63;
      gload_lds16((const char*)A + ((size_t)(brow + row) * K + kt) * 2 + colb,
                  (char*)As + o);
      gload_lds16((const char*)Bm + ((size_t)(bcol + row) * K + kt) * 2 + colb,
                  (char*)Bs + o);
    }
    __syncthreads();
    bf16x8 av[4], bv[4];
#pragma unroll
    for (int m = 0; m < 4; ++m)
      av[m] = *(const bf16x8*)(As + (wr + m * 16 + lq) * 32 + g * 8);
#pragma unroll
    for (int n = 0; n < 4; ++n)
      bv[n] = *(const bf16x8*)(Bs + (wc + n * 16 + lq) * 32 + g * 8);
#pragma unroll
    for (int m = 0; m < 4; ++m)
#pragma unroll
      for (int n = 0; n < 4; ++n)
        acc[m][n] = __builtin_amdgcn_mfma_f32_16x16x32_bf16(av[m], bv[n], acc[m][n], 0, 0, 0);
  }

#pragma unroll
  for (int m = 0; m < 4; ++m) {
#pragma unroll
    for (int n = 0; n < 4; ++n) {
      int col = bcol + wc + n * 16 + lq;
      float bb = bias[col];
      int row0 = brow + wr + m * 16 + g * 4;
#pragma unroll
      for (int i = 0; i < 4; ++i)
        out[(size_t)(row0 + i) * N + col] = acc[m][n][i] + bb;
    }
  }
}

// ---------------- Flash attention v6 (causal + padding mask) ----------------
// grid 1024 = 16 q-tiles x 64 bh, 256 threads = 4 waves x 32 q-rows (QBLK=128).
// 32x32x16 MFMA, swapped QK^T, split-half S, in-register softmax.
// Full-grid residency: double-buffered K/V (32.8KB LDS) + launch_bounds(256,4)
// -> 4 blocks/CU -> all 1024 blocks co-resident. Heavy-first Latin-square qi
// map balances per-CU work. One barrier per tile, counted staging.
// C/D layout (m74/m101): col = lane&31, row = (r&3) + 8*(r>>2) + 4*(lane>>5).
__global__ __launch_bounds__(256, 4)
void attn_fwd(const __bf16* __restrict__ Q, const __bf16* __restrict__ K,
              const __bf16* __restrict__ Vt, const int* __restrict__ pm,
              __bf16* __restrict__ Y) {
  __shared__ __bf16 Ks[2][64 * 64];   // 16 KiB
  __shared__ __bf16 Vs[2][64 * 64];   // 16 KiB
  __shared__ int flg;
  const int tid = threadIdx.x, wid = tid >> 6, lane = tid & 63;
  const int l31 = lane & 31, hi = lane >> 5;
  const int bx = blockIdx.x;
  const int bh = bx & 63, jj = bx >> 6;          // jj 0..15
  const int qi = 15 - (4 * (jj >> 2) + ((jj + (jj >> 2)) & 3));
  const int b_ = bh >> 4, h_ = bh & 15;
  const __bf16* Qb = Q + (size_t)bh * TT * HD;
  const __bf16* Kb = K + (size_t)bh * TT * HD;
  const __bf16* Vb = Vt + (size_t)bh * HD * TT;
  const int* pmb = pm + b_ * TT;

  const int so = tid * 16;                 // 16B chunk, 0..4080
  const int srow = tid >> 3;               // 0..31
  const int scol = (so & 127) ^ ((srow & 7) << 4);   // inverse-swizzled src col

  const int q0 = qi << 7;
  const int qw = q0 + wid * 32;            // this wave's 32 q-rows
  const int ntiles = 2 * qi + 2;           // >= 2 always
  const int sw0 = (l31 & 7) << 4;

  // Q fragments: lane holds Q[qw+l31][16s + 8hi .. +7], s=0..3
  bf16x8 qf[4];
#pragma unroll
  for (int s = 0; s < 4; ++s)
    qf[s] = *(const bf16x8*)(Qb + (size_t)(qw + l31) * HD + s * 16 + hi * 8);
  SB0;   // pin qf loads above the staging issues (vmcnt accounting)

  // padding-mask block check: 256 threads x 2 int4 cover the 2048-int pm row
  int4 pa4 = ((const int4*)pmb)[tid];
  int4 pb4 = ((const int4*)pmb)[tid + 256];
  bool okp = pa4.x && pa4.y && pa4.z && pa4.w &&
             pb4.x && pb4.y && pb4.z && pb4.w;
  if (tid == 0) flg = 1;
  __syncthreads();
  if (!okp) flg = 0;                       // benign race (all writers store 0)

  // prologue: stage tile 0 into buf 0 (4 gloads: 2 K + 2 V)
  {
    char* kd = (char*)&Ks[0][0] + so;
    char* vd = (char*)&Vs[0][0] + so;
#pragma unroll
    for (int j = 0; j < 2; ++j) {
      gload_lds16((const char*)Kb + (size_t)(srow + 32 * j) * 128 + scol,
                  kd + j * 4096);
      gload_lds16((const char*)Vb + (size_t)(srow + 32 * j) * (TT * 2) + scol,
                  vd + j * 4096);
    }
  }
  __syncthreads();                         // tile 0 staged everywhere; flg final
  const bool allones = (flg != 0);

  f32x16 o0 = {}, o1 = {};                 // O[q=crow(r,hi)][d = l31 | 32+l31]
  f32x16 vzero = {};                       // persistent zero C-operand
  float lsum = 0.f;                        // partial row-sum (this lane-half)
  float m = -INFINITY;                     // running max for q = qw+l31

  int cur = 0;
#pragma unroll 1
  for (int t = 0; t < ntiles; ++t) {
    const int kv0 = t << 6;
    // ---- own stage(t) done (issued a full compute phase ago -> cheap) ----
    WAITV0;
    __builtin_amdgcn_s_barrier(); SB0;  // tile t staged AND t-1 reads done
    // ---- issue stage(t+1) into buf[cur^1] (tile t-1's slot, now free) ----
    if (t + 1 < ntiles) {
      char* kd = (char*)&Ks[0][0] + (cur ^ 1) * 8192 + so;
      char* vd = (char*)&Vs[0][0] + (cur ^ 1) * 8192 + so;
      const size_t nk = (size_t)(kv0 + 64);
#pragma unroll
      for (int j = 0; j < 2; ++j) {
        gload_lds16((const char*)Kb + (nk + srow + 32 * j) * 128 + scol,
                    kd + j * 4096);
        gload_lds16((const char*)Vb + (size_t)(srow + 32 * j) * (TT * 2) +
                        nk * 2 + scol,
                    vd + j * 4096);
      }
    }

    unsigned long long bits = ~0ull;
    if (__builtin_expect(!allones, 0))     // rare slow path
      bits = __ballot(pmb[kv0 + lane] != 0);

    if (kv0 <= qw + 31) {                  // wave-uniform participation
      const char* VsC = (const char*)&Vs[0][0] + cur * 8192;

#pragma unroll
      for (int h = 0; h < 2; ++h) {
        const int kvh = kv0 + 32 * h;
        if (kvh <= qw + 31) {              // wave-uniform per-half gate
          // ---- QK^T (swapped): S[kvh+crow][q=l31] ----
          const char* KsC =
              (const char*)&Ks[0][0] + cur * 8192 + (32 * h + l31) * 128;
          f32x16 S;
          __builtin_amdgcn_s_setprio(1);
          {
            bf16x8 k0 = *(const bf16x8*)(KsC + ((16 * hi) ^ sw0));
            S = __builtin_amdgcn_mfma_f32_32x32x16_bf16(k0, qf[0], vzero, 0, 0, 0);
          }
#pragma unroll
          for (int s = 1; s < 4; ++s) {
            bf16x8 kf = *(const bf16x8*)(KsC + ((32 * s + 16 * hi) ^ sw0));
            S = __builtin_amdgcn_mfma_f32_32x32x16_bf16(kf, qf[s], S, 0, 0, 0);
          }
          __builtin_amdgcn_s_setprio(0);

          // ---- masks ----
          if (__builtin_expect(bits != ~0ull, 0)) {   // padding (rare)
#pragma unroll
            for (int r = 0; r < 16; ++r) {
              const int c = (r & 3) + 8 * (r >> 2);
              if (!((bits >> (32 * h + c + 4 * hi)) & 1ull)) S[r] = -INFINITY;
            }
          }
          if (kvh + 31 > qw) {             // causal diag (wave-uniform)
            const int thr = qw + l31 - kvh - 4 * hi;
#pragma unroll
            for (int r = 0; r < 16; ++r) {
              const int c = (r & 3) + 8 * (r >> 2);
              S[r] = (c <= thr) ? S[r] : -INFINITY;
            }
          }

          // ---- row max via packed-f32 tree + defer-rescale check ----
          f32x2 x0 = {S[0], S[1]},  x1 = {S[2], S[3]};
          f32x2 x2 = {S[4], S[5]},  x3 = {S[6], S[7]};
          f32x2 x4 = {S[8], S[9]},  x5 = {S[10], S[11]};
          f32x2 x6 = {S[12], S[13]}, x7 = {S[14], S[15]};
          x0 = max2(x0, x4); x1 = max2(x1, x5);
          x2 = max2(x2, x6); x3 = max2(x3, x7);
          x0 = max2(x0, x2); x1 = max2(x1, x3);
          x0 = max2(x0, x1);
          float pmax = fmaxf(x0[0], x0[1]);
          if (!__all(pmax <= m + 8.f)) {
            float nm = fmaxf(pmax, __shfl_xor(pmax, 32));  // full row max
            float mn = fmaxf(m, nm);
            float c = fast_exp2(m - mn);
            m = mn;
            lsum *= c;
#pragma unroll
            for (int r = 0; r < 16; ++r) {
              float cr = __shfl(c, (r & 3) + 8 * (r >> 2) + 4 * hi);
              o0[r] *= cr;
              o1[r] *= cr;
            }
          }

          // ---- P = exp2(S - m) (packed sub, trans exp) ----
          const f32x2 mm = {m, m};
#pragma unroll
          for (int r = 0; r < 16; r += 2) {
            f32x2 u = {S[r], S[r + 1]};
            u -= mm;                      // v_pk_add_f32
            S[r] = fast_exp2(u[0]);
            S[r + 1] = fast_exp2(u[1]);
          }
          // ---- in-lane row-sum via packed-f32 tree ----
          {
            f32x2 u0 = {S[0], S[1]},  u1 = {S[2], S[3]};
            f32x2 u2 = {S[4], S[5]},  u3 = {S[6], S[7]};
            f32x2 u4 = {S[8], S[9]},  u5 = {S[10], S[11]};
            f32x2 u6 = {S[12], S[13]}, u7 = {S[14], S[15]};
            u0 += u4; u1 += u5; u2 += u6; u3 += u7;
            u0 += u2; u1 += u3;
            u0 += u1;
            lsum += u0[0] + u0[1];
          }

          // ---- PV: build A-fragments (validated select+shfl_xor exchange) ----
          __builtin_amdgcn_s_setprio(1);
#pragma unroll
          for (int s = 0; s < 2; ++s) {
            int A0 = cvt_pk_bf16(S[8 * s + 0], S[8 * s + 1]);
            int A1 = cvt_pk_bf16(S[8 * s + 2], S[8 * s + 3]);
            int B0 = cvt_pk_bf16(S[8 * s + 4], S[8 * s + 5]);
            int B1 = cvt_pk_bf16(S[8 * s + 6], S[8 * s + 7]);
            // exchange across lane+-32: lo lanes need A-pairs of BOTH halves,
            // hi lanes need B-pairs of BOTH halves.
            int s0 = hi ? A0 : B0, s1 = hi ? A1 : B1;
            int e0 = __shfl_xor(s0, 32), e1 = __shfl_xor(s1, 32);
            i32x4 wv;
            wv[0] = hi ? e0 : A0;
            wv[1] = hi ? e1 : A1;
            wv[2] = hi ? B0 : e0;
            wv[3] = hi ? B1 : e1;
            bf16x8 pa = __builtin_bit_cast(bf16x8, wv);
            const int co = 64 * h + 32 * s + 16 * hi;   // kv byte offset
            bf16x8 v0 = *(const bf16x8*)(VsC + l31 * 128 + (co ^ sw0));
            bf16x8 v1 = *(const bf16x8*)(VsC + (32 + l31) * 128 + (co ^ sw0));
            o0 = __builtin_amdgcn_mfma_f32_32x32x16_bf16(pa, v0, o0, 0, 0, 0);
            o1 = __builtin_amdgcn_mfma_f32_32x32x16_bf16(pa, v1, o1, 0, 0, 0);
          }
          __builtin_amdgcn_s_setprio(0);
        }
      }
    }
    SB0;   // pin this tile's LDS reads above next iteration's barrier
    cur ^= 1;
  }

  // epilogue: combine lane-halves' row-sums, normalize + store
  float linv = 1.f / (lsum + __shfl_xor(lsum, 32));
#pragma unroll
  for (int r = 0; r < 16; ++r) {
    const int crow = (r & 3) + 8 * (r >> 2) + 4 * hi;
    float ir = __shfl(linv, crow);
    const int qrow = qw + crow;
    __bf16* yp = Y + ((size_t)(b_ * TT + qrow)) * CC + h_ * HD + l31;
    yp[0]  = (__bf16)(o0[r] * ir);
    yp[32] = (__bf16)(o1[r] * ir);
  }
}

// ---------------- launch ----------------
extern "C" void kernel_launch(void* const* d_in, const int* in_sizes, int n_in,
                              void* d_out, int out_size, void* d_ws, size_t ws_size,
                              hipStream_t stream) {
  (void)in_sizes; (void)n_in; (void)out_size; (void)ws_size;
  const float* x  = (const float*)d_in[0];
  const float* Wk = (const float*)d_in[1];
  const float* bk = (const float*)d_in[2];
  const float* Wq = (const float*)d_in[3];
  const float* bq = (const float*)d_in[4];
  const float* Wv = (const float*)d_in[5];
  const float* bv = (const float*)d_in[6];
  const float* Wp = (const float*)d_in[7];
  const float* bp = (const float*)d_in[8];
  const int* pmask = (const int*)d_in[9];

  char* ws = (char*)d_ws;
  const size_t MB = 1024 * 1024;
  __bf16* xb   = (__bf16*)(ws);            // 16MB; reused as attn-out y
  __bf16* wqkv = (__bf16*)(ws + 16 * MB);  // 6MB  [3072][1024] (q,k,v concat)
  __bf16* wpb  = (__bf16*)(ws + 22 * MB);  // 2MB
  __bf16* qb   = (__bf16*)(ws + 24 * MB);  // 16MB [B,H,T,HD]
  __bf16* kb   = qb + ((size_t)1 << 23);   // 16MB @40MB
  __bf16* vtb  = (__bf16*)(ws + 56 * MB);  // 16MB [B,H,HD,T] (written by gemm_qkv)
  __bf16* yb   = xb;                       // attn out overwrites x

  int n4 = (MM * CC) / 4;                  // 2097152
  cvt_f32_bf16<<<(n4 + 255) / 256, 256, 0, stream>>>(x, xb, n4);
  cvt_w4<<<dim3((CC * CC / 4) / 256, 4), 256, 0, stream>>>(
      Wq, Wk, Wv, Wp, wqkv, wpb);

  // fused QKV projection + V-transpose epilogue (256x128 tiles, grid 768)
  gemm_qkv<<<(MM / 256) * (3 * CC / 128), 512, 0, stream>>>(
      xb, wqkv, bq, bk, bv, qb, vtb);

  attn_fwd<<<NQT2 * BB * HH, 256, 0, stream>>>(qb, kb, vtb, pmask, yb);

  gemm_proj<<<(MM / 128) * (CC / 128), 256, 0, stream>>>(
      yb, wpb, bp, (float*)d_out, MM, CC, CC);
}

// Round 11
// 174.624 us; speedup vs baseline: 2.7251x; 2.7251x over previous
//
#include <hip/hip_runtime.h>
#include <hip/hip_bf16.h>
#include <math.h>
#include <stdint.h>

// Problem constants (reference: B=4, T=2048, C=1024, H=16, HD=64)
#define BB 4
#define TT 2048
#define CC 1024
#define HH 16
#define HD 64
#define MM (BB*TT)   // 8192
#define NQT2 16      // T / 128 q-tiles for attention (QBLK=128)
#define SCQ 0.180336878f   // (1/sqrt(HD)) * log2(e): Q pre-scale for exp2-domain softmax

using f32x2  = __attribute__((ext_vector_type(2))) float;
using f32x4  = __attribute__((ext_vector_type(4))) float;
using f32x16 = __attribute__((ext_vector_type(16))) float;
using i32x4  = __attribute__((ext_vector_type(4))) int;
using bf16x4 = __attribute__((ext_vector_type(4))) __bf16;
using bf16x8 = __attribute__((ext_vector_type(8))) __bf16;

__device__ __forceinline__ float fast_exp2(float x) {
  return __builtin_amdgcn_exp2f(x);   // v_exp_f32 (native exp2 on gfx950)
}

__device__ __forceinline__ int cvt_pk_bf16(float lo, float hi_) {
  int r;
  asm("v_cvt_pk_bf16_f32 %0, %1, %2" : "=v"(r) : "v"(lo), "v"(hi_));
  return r;   // low 16 = bf16(lo), high 16 = bf16(hi_)
}

__device__ __forceinline__ f32x2 max2(f32x2 a, f32x2 b) {
  return __builtin_elementwise_max(a, b);   // v_pk_max_f32
}

__device__ __forceinline__ void gload_lds16(const void* g, void* l) {
  __builtin_amdgcn_global_load_lds(
      (__attribute__((address_space(1))) void*)(void*)(g),
      (__attribute__((address_space(3))) void*)(l), 16, 0, 0);
}

// ---------------- fp32 -> bf16 converts ----------------
__global__ __launch_bounds__(256)
void cvt_f32_bf16(const float* __restrict__ s, __bf16* __restrict__ d, int n4) {
  int i = blockIdx.x * 256 + threadIdx.x;
  if (i >= n4) return;
  float4 v = ((const float4*)s)[i];
  bf16x4 o;
  o[0] = (__bf16)v.x; o[1] = (__bf16)v.y; o[2] = (__bf16)v.z; o[3] = (__bf16)v.w;
  *(bf16x4*)(d + (size_t)i * 4) = o;
}

// 4 weights in one launch; Wq scaled by SCQ and Wq/Wk/Wv written into the
// contiguous [3072][1024] concat buffer (order q,k,v); Wp separate.
__global__ __launch_bounds__(256)
void cvt_w4(const float* __restrict__ Wq, const float* __restrict__ Wk,
            const float* __restrict__ Wv, const float* __restrict__ Wp,
            __bf16* __restrict__ wqkv, __bf16* __restrict__ wpb) {
  int which = blockIdx.y;
  const float* s = which == 0 ? Wq : which == 1 ? Wk : which == 2 ? Wv : Wp;
  __bf16* d = which == 3 ? wpb : wqkv + (size_t)which * CC * CC;
  float sc = which == 0 ? SCQ : 1.f;
  int i = blockIdx.x * 256 + threadIdx.x;   // grid.x = (CC*CC/4)/256 = 1024
  float4 v = ((const float4*)s)[i];
  bf16x4 o;
  o[0] = (__bf16)(v.x * sc); o[1] = (__bf16)(v.y * sc);
  o[2] = (__bf16)(v.z * sc); o[3] = (__bf16)(v.w * sc);
  *(bf16x4*)(d + (size_t)i * 4) = o;
}

#define WAITV0 asm volatile("s_waitcnt vmcnt(0)" ::: "memory")
#define SB0    __builtin_amdgcn_sched_barrier(0)

// ==== QKV GEMM v11: r9 m97-clone + conflict-free reads + 16.9KB LDS =========
// C[8192,3072] = A[8192,1024] x Wqkv[3072,1024]^T + bias.
// r10 post-mortem: launch_bounds(512,6) spilled acc (VGPR 40, 1.2GB scratch).
// v11 reverts to r9's validated 128x128 / 256-thread skeleton and applies the
// two r10-validated fixes WITHOUT the occupancy gamble:
//  * slot-swizzle staging/read pair (numerically proven in r10): LDS dest
//    linear, global source col inverse-swizzled, read slot=(g+(row>>1))&3.
//    Kills r9's 6.4M bank-conflict cycles (8-way -> 2-way=free).
//  * lt transpose buffer ALIASES As/Bs (pre-write __syncthreads closes WAR):
//    LDS 33.3 -> 16.9KB -> up to 8 blocks/CU (VGPR 60) -> all 6 blocks/CU of
//    the 1536-grid co-resident; cross-block overlap hides the zero-prefetch
//    staging latency (the r9 structural stall).
// proj 0/1 (Q,K): bf16 head-split store; proj 2 (V): 2x 64-col LDS transpose
// chunks -> Vt[bh][d][t].
__global__ __launch_bounds__(256, 2)
void gemm_qkv(const __bf16* __restrict__ A, const __bf16* __restrict__ Bm,
              const float* __restrict__ b0, const float* __restrict__ b1,
              const float* __restrict__ b2, __bf16* __restrict__ out,
              __bf16* __restrict__ vt) {
  __shared__ __bf16 U[8448];         // 16.9KB: As[4096]+Bs[4096]; lt[8320] alias
  __bf16* As = U;                    // [128][32]
  __bf16* Bs = U + 4096;             // [128][32]
  const int tid = threadIdx.x;
  const int wid = tid >> 6, lane = tid & 63;
  const int g = lane >> 4, lq = lane & 15;
  // XCD-chunk swizzle: 1536 blocks = 8 XCDs x 192 contiguous logicals
  const int bx0 = blockIdx.x;
  const int bx = (bx0 & 7) * 192 + (bx0 >> 3);
  const int bm = bx / 24, bn = bx % 24;
  const int brow = bm << 7, bcol = bn << 7;
  const int wr = (wid >> 1) << 6, wc = (wid & 1) << 6;

  // staging: thread handles chunks c and c+256 per array (16B each).
  // chunk c -> LDS row c>>2, slot c&3 (linear dest); global source column is
  // inverse-swizzled so read-side slot=(g+(row>>1))&3 recovers K-chunk g.
  const int c0 = tid, c1 = tid + 256;
  const int r0 = c0 >> 2, s0_ = (((c0 & 3) - (r0 >> 1)) & 3) << 4;
  const int r1 = c1 >> 2, s1_ = (((c1 & 3) - (r1 >> 1)) & 3) << 4;

  f32x4 acc[4][4] = {};

  for (int kt = 0; kt < CC; kt += 32) {
    __syncthreads();
    gload_lds16((const char*)A + (size_t)(brow + r0) * 2048 + kt * 2 + s0_,
                (char*)As + c0 * 16);
    gload_lds16((const char*)A + (size_t)(brow + r1) * 2048 + kt * 2 + s1_,
                (char*)As + c1 * 16);
    gload_lds16((const char*)Bm + (size_t)(bcol + r0) * 2048 + kt * 2 + s0_,
                (char*)Bs + c0 * 16);
    gload_lds16((const char*)Bm + (size_t)(bcol + r1) * 2048 + kt * 2 + s1_,
                (char*)Bs + c1 * 16);
    __syncthreads();
    bf16x8 av[4], bv[4];
#pragma unroll
    for (int m = 0; m < 4; ++m) {
      int row = wr + m * 16 + lq;
      int sl = (g + (row >> 1)) & 3;
      av[m] = *(const bf16x8*)((const char*)As + row * 64 + sl * 16);
    }
#pragma unroll
    for (int n = 0; n < 4; ++n) {
      int row = wc + n * 16 + lq;
      int sl = (g + (row >> 1)) & 3;
      bv[n] = *(const bf16x8*)((const char*)Bs + row * 64 + sl * 16);
    }
#pragma unroll
    for (int m = 0; m < 4; ++m)
#pragma unroll
      for (int n = 0; n < 4; ++n)
        acc[m][n] = __builtin_amdgcn_mfma_f32_16x16x32_bf16(av[m], bv[n], acc[m][n], 0, 0, 0);
  }

  const int proj = bn >> 3;   // uniform per block (8 x 128 = 1024 cols / proj)
  if (proj < 2) {
    // epilogue: bias + bf16 head-split store [proj][B,H,T,HD]
    const float* bias = proj == 0 ? b0 : b1;
    const float bsc = proj == 0 ? SCQ : 1.f;
#pragma unroll
    for (int n = 0; n < 4; ++n) {
      int col = bcol + wc + n * 16 + lq;
      int cw = col & (CC - 1);
      float bb = bias[cw] * bsc;
      int h_ = cw >> 6, d_ = cw & (HD - 1);
#pragma unroll
      for (int m = 0; m < 4; ++m) {
        int row0 = brow + wr + m * 16 + g * 4;
#pragma unroll
        for (int i = 0; i < 4; ++i) {
          int row = row0 + i;
          int b_ = row >> 11, t_ = row & (TT - 1);
          out[((size_t)proj << 23) +
              ((((size_t)b_ * HH + h_) * TT + t_) << 6) + d_] =
              (__bf16)(acc[m][n][i] + bb);
        }
      }
    }
  } else {
    // V: transpose 128x128 tile through lt (2 chunks of 64 cols = 1 head
    // each) -> Vt[bh][d][t] coalesced. lt ALIASES As/Bs: barrier first.
    __syncthreads();                             // all K-loop LDS reads done
    __bf16* lt = U;                              // [64 cols][130 rows]
    const int cv0 = (bn & 7) << 7;               // col offset within V region
    const int b_ = brow >> 11, t0 = brow & (TT - 1);
    const int hbase = (bn & 7) << 1;
    const int rd_d = tid >> 2, rd_tb = (tid & 3) << 5;   // 64 d x 128 t
#pragma unroll
    for (int cc = 0; cc < 2; ++cc) {
      if ((wid & 1) == cc) {                     // 2 writer waves per chunk
#pragma unroll
        for (int n = 0; n < 4; ++n) {
          int c = (n << 4) + lq;                 // 0..63 within chunk
          float bb = b2[cv0 + (cc << 6) + c];
#pragma unroll
          for (int m = 0; m < 4; ++m) {
            int r = wr + (m << 4) + (g << 2);    // 0..127 over both writers
            bf16x4 pk;
#pragma unroll
            for (int i = 0; i < 4; ++i)
              pk[i] = (__bf16)(acc[m][n][i] + bb);
            *(bf16x4*)(lt + c * 130 + r) = pk;
          }
        }
      }
      __syncthreads();
      // readers: all 256 threads; d = tid>>2, 32 t-elems each
      __bf16* dst = vt + (((size_t)((b_ * HH + hbase + cc) * HD + rd_d)) << 11)
                       + t0 + rd_tb;
      const __bf16* srcl = lt + rd_d * 130 + rd_tb;
#pragma unroll
      for (int j = 0; j < 4; ++j)
        *(bf16x8*)(dst + j * 8) = *(const bf16x8*)(srcl + j * 8);
      __syncthreads();
    }
  }
}

// ---------------- proj GEMM (m97 structure): fp32 out ----------------
__global__ __launch_bounds__(256, 2)
void gemm_proj(const __bf16* __restrict__ A, const __bf16* __restrict__ Bm,
               const float* __restrict__ bias, float* __restrict__ out,
               int M, int N, int K) {
  __shared__ __bf16 As[128 * 32];
  __shared__ __bf16 Bs[128 * 32];
  const int tid = threadIdx.x;
  const int wid = tid >> 6, lane = tid & 63;
  const int g = lane >> 4, lq = lane & 15;
  const int nbn = N >> 7;
  // XCD-chunk swizzle (bijective when gridDim.x % 8 == 0; our launch: 512)
  int bx = blockIdx.x;
  const int nb = gridDim.x;
  if ((nb & 7) == 0) { const int q = nb >> 3; bx = (bx & 7) * q + (bx >> 3); }
  const int brow = (bx / nbn) << 7;
  const int bcol = (bx % nbn) << 7;
  const int wr = (wid >> 1) << 6, wc = (wid & 1) << 6;

  f32x4 acc[4][4] = {};

  const int o0 = wid * 2048 + lane * 16;
  for (int kt = 0; kt < K; kt += 32) {
    __syncthreads();
#pragma unroll
    for (int j = 0; j < 2; ++j) {
      int o = o0 + j * 1024;
      int row = o >> 6, colb = o & 63;
      gload_lds16((const char*)A + ((size_t)(brow + row) * K + kt) * 2 + colb,
                  (char*)As + o);
      gload_lds16((const char*)Bm + ((size_t)(bcol + row) * K + kt) * 2 + colb,
                  (char*)Bs + o);
    }
    __syncthreads();
    bf16x8 av[4], bv[4];
#pragma unroll
    for (int m = 0; m < 4; ++m)
      av[m] = *(const bf16x8*)(As + (wr + m * 16 + lq) * 32 + g * 8);
#pragma unroll
    for (int n = 0; n < 4; ++n)
      bv[n] = *(const bf16x8*)(Bs + (wc + n * 16 + lq) * 32 + g * 8);
#pragma unroll
    for (int m = 0; m < 4; ++m)
#pragma unroll
      for (int n = 0; n < 4; ++n)
        acc[m][n] = __builtin_amdgcn_mfma_f32_16x16x32_bf16(av[m], bv[n], acc[m][n], 0, 0, 0);
  }

#pragma unroll
  for (int m = 0; m < 4; ++m) {
#pragma unroll
    for (int n = 0; n < 4; ++n) {
      int col = bcol + wc + n * 16 + lq;
      float bb = bias[col];
      int row0 = brow + wr + m * 16 + g * 4;
#pragma unroll
      for (int i = 0; i < 4; ++i)
        out[(size_t)(row0 + i) * N + col] = acc[m][n][i] + bb;
    }
  }
}

// ---------------- Flash attention v6 (causal + padding mask) ----------------
// grid 1024 = 16 q-tiles x 64 bh, 256 threads = 4 waves x 32 q-rows (QBLK=128).
// 32x32x16 MFMA, swapped QK^T, split-half S, in-register softmax.
// Full-grid residency: double-buffered K/V (32.8KB LDS) + launch_bounds(256,4)
// -> 4 blocks/CU -> all 1024 blocks co-resident. Heavy-first Latin-square qi
// map balances per-CU work. One barrier per tile, counted staging.
// C/D layout (m74/m101): col = lane&31, row = (r&3) + 8*(r>>2) + 4*(lane>>5).
__global__ __launch_bounds__(256, 4)
void attn_fwd(const __bf16* __restrict__ Q, const __bf16* __restrict__ K,
              const __bf16* __restrict__ Vt, const int* __restrict__ pm,
              __bf16* __restrict__ Y) {
  __shared__ __bf16 Ks[2][64 * 64];   // 16 KiB
  __shared__ __bf16 Vs[2][64 * 64];   // 16 KiB
  __shared__ int flg;
  const int tid = threadIdx.x, wid = tid >> 6, lane = tid & 63;
  const int l31 = lane & 31, hi = lane >> 5;
  const int bx = blockIdx.x;
  const int bh = bx & 63, jj = bx >> 6;          // jj 0..15
  const int qi = 15 - (4 * (jj >> 2) + ((jj + (jj >> 2)) & 3));
  const int b_ = bh >> 4, h_ = bh & 15;
  const __bf16* Qb = Q + (size_t)bh * TT * HD;
  const __bf16* Kb = K + (size_t)bh * TT * HD;
  const __bf16* Vb = Vt + (size_t)bh * HD * TT;
  const int* pmb = pm + b_ * TT;

  const int so = tid * 16;                 // 16B chunk, 0..4080
  const int srow = tid >> 3;               // 0..31
  const int scol = (so & 127) ^ ((srow & 7) << 4);   // inverse-swizzled src col

  const int q0 = qi << 7;
  const int qw = q0 + wid * 32;            // this wave's 32 q-rows
  const int ntiles = 2 * qi + 2;           // >= 2 always
  const int sw0 = (l31 & 7) << 4;

  // Q fragments: lane holds Q[qw+l31][16s + 8hi .. +7], s=0..3
  bf16x8 qf[4];
#pragma unroll
  for (int s = 0; s < 4; ++s)
    qf[s] = *(const bf16x8*)(Qb + (size_t)(qw + l31) * HD + s * 16 + hi * 8);
  SB0;   // pin qf loads above the staging issues (vmcnt accounting)

  // padding-mask block check: 256 threads x 2 int4 cover the 2048-int pm row
  int4 pa4 = ((const int4*)pmb)[tid];
  int4 pb4 = ((const int4*)pmb)[tid + 256];
  bool okp = pa4.x && pa4.y && pa4.z && pa4.w &&
             pb4.x && pb4.y && pb4.z && pb4.w;
  if (tid == 0) flg = 1;
  __syncthreads();
  if (!okp) flg = 0;                       // benign race (all writers store 0)

  // prologue: stage tile 0 into buf 0 (4 gloads: 2 K + 2 V)
  {
    char* kd = (char*)&Ks[0][0] + so;
    char* vd = (char*)&Vs[0][0] + so;
#pragma unroll
    for (int j = 0; j < 2; ++j) {
      gload_lds16((const char*)Kb + (size_t)(srow + 32 * j) * 128 + scol,
                  kd + j * 4096);
      gload_lds16((const char*)Vb + (size_t)(srow + 32 * j) * (TT * 2) + scol,
                  vd + j * 4096);
    }
  }
  __syncthreads();                         // tile 0 staged everywhere; flg final
  const bool allones = (flg != 0);

  f32x16 o0 = {}, o1 = {};                 // O[q=crow(r,hi)][d = l31 | 32+l31]
  f32x16 vzero = {};                       // persistent zero C-operand
  float lsum = 0.f;                        // partial row-sum (this lane-half)
  float m = -INFINITY;                     // running max for q = qw+l31

  int cur = 0;
#pragma unroll 1
  for (int t = 0; t < ntiles; ++t) {
    const int kv0 = t << 6;
    // ---- own stage(t) done (issued a full compute phase ago -> cheap) ----
    WAITV0;
    __builtin_amdgcn_s_barrier(); SB0;  // tile t staged AND t-1 reads done
    // ---- issue stage(t+1) into buf[cur^1] (tile t-1's slot, now free) ----
    if (t + 1 < ntiles) {
      char* kd = (char*)&Ks[0][0] + (cur ^ 1) * 8192 + so;
      char* vd = (char*)&Vs[0][0] + (cur ^ 1) * 8192 + so;
      const size_t nk = (size_t)(kv0 + 64);
#pragma unroll
      for (int j = 0; j < 2; ++j) {
        gload_lds16((const char*)Kb + (nk + srow + 32 * j) * 128 + scol,
                    kd + j * 4096);
        gload_lds16((const char*)Vb + (size_t)(srow + 32 * j) * (TT * 2) +
                        nk * 2 + scol,
                    vd + j * 4096);
      }
    }

    unsigned long long bits = ~0ull;
    if (__builtin_expect(!allones, 0))     // rare slow path
      bits = __ballot(pmb[kv0 + lane] != 0);

    if (kv0 <= qw + 31) {                  // wave-uniform participation
      const char* VsC = (const char*)&Vs[0][0] + cur * 8192;

#pragma unroll
      for (int h = 0; h < 2; ++h) {
        const int kvh = kv0 + 32 * h;
        if (kvh <= qw + 31) {              // wave-uniform per-half gate
          // ---- QK^T (swapped): S[kvh+crow][q=l31] ----
          const char* KsC =
              (const char*)&Ks[0][0] + cur * 8192 + (32 * h + l31) * 128;
          f32x16 S;
          __builtin_amdgcn_s_setprio(1);
          {
            bf16x8 k0 = *(const bf16x8*)(KsC + ((16 * hi) ^ sw0));
            S = __builtin_amdgcn_mfma_f32_32x32x16_bf16(k0, qf[0], vzero, 0, 0, 0);
          }
#pragma unroll
          for (int s = 1; s < 4; ++s) {
            bf16x8 kf = *(const bf16x8*)(KsC + ((32 * s + 16 * hi) ^ sw0));
            S = __builtin_amdgcn_mfma_f32_32x32x16_bf16(kf, qf[s], S, 0, 0, 0);
          }
          __builtin_amdgcn_s_setprio(0);

          // ---- masks ----
          if (__builtin_expect(bits != ~0ull, 0)) {   // padding (rare)
#pragma unroll
            for (int r = 0; r < 16; ++r) {
              const int c = (r & 3) + 8 * (r >> 2);
              if (!((bits >> (32 * h + c + 4 * hi)) & 1ull)) S[r] = -INFINITY;
            }
          }
          if (kvh + 31 > qw) {             // causal diag (wave-uniform)
            const int thr = qw + l31 - kvh - 4 * hi;
#pragma unroll
            for (int r = 0; r < 16; ++r) {
              const int c = (r & 3) + 8 * (r >> 2);
              S[r] = (c <= thr) ? S[r] : -INFINITY;
            }
          }

          // ---- row max via packed-f32 tree + defer-rescale check ----
          f32x2 x0 = {S[0], S[1]},  x1 = {S[2], S[3]};
          f32x2 x2 = {S[4], S[5]},  x3 = {S[6], S[7]};
          f32x2 x4 = {S[8], S[9]},  x5 = {S[10], S[11]};
          f32x2 x6 = {S[12], S[13]}, x7 = {S[14], S[15]};
          x0 = max2(x0, x4); x1 = max2(x1, x5);
          x2 = max2(x2, x6); x3 = max2(x3, x7);
          x0 = max2(x0, x2); x1 = max2(x1, x3);
          x0 = max2(x0, x1);
          float pmax = fmaxf(x0[0], x0[1]);
          if (!__all(pmax <= m + 8.f)) {
            float nm = fmaxf(pmax, __shfl_xor(pmax, 32));  // full row max
            float mn = fmaxf(m, nm);
            float c = fast_exp2(m - mn);
            m = mn;
            lsum *= c;
#pragma unroll
            for (int r = 0; r < 16; ++r) {
              float cr = __shfl(c, (r & 3) + 8 * (r >> 2) + 4 * hi);
              o0[r] *= cr;
              o1[r] *= cr;
            }
          }

          // ---- P = exp2(S - m) (packed sub, trans exp) ----
          const f32x2 mm = {m, m};
#pragma unroll
          for (int r = 0; r < 16; r += 2) {
            f32x2 u = {S[r], S[r + 1]};
            u -= mm;                      // v_pk_add_f32
            S[r] = fast_exp2(u[0]);
            S[r + 1] = fast_exp2(u[1]);
          }
          // ---- in-lane row-sum via packed-f32 tree ----
          {
            f32x2 u0 = {S[0], S[1]},  u1 = {S[2], S[3]};
            f32x2 u2 = {S[4], S[5]},  u3 = {S[6], S[7]};
            f32x2 u4 = {S[8], S[9]},  u5 = {S[10], S[11]};
            f32x2 u6 = {S[12], S[13]}, u7 = {S[14], S[15]};
            u0 += u4; u1 += u5; u2 += u6; u3 += u7;
            u0 += u2; u1 += u3;
            u0 += u1;
            lsum += u0[0] + u0[1];
          }

          // ---- PV: build A-fragments (validated select+shfl_xor exchange) ----
          __builtin_amdgcn_s_setprio(1);
#pragma unroll
          for (int s = 0; s < 2; ++s) {
            int A0 = cvt_pk_bf16(S[8 * s + 0], S[8 * s + 1]);
            int A1 = cvt_pk_bf16(S[8 * s + 2], S[8 * s + 3]);
            int B0 = cvt_pk_bf16(S[8 * s + 4], S[8 * s + 5]);
            int B1 = cvt_pk_bf16(S[8 * s + 6], S[8 * s + 7]);
            // exchange across lane+-32: lo lanes need A-pairs of BOTH halves,
            // hi lanes need B-pairs of BOTH halves.
            int s0 = hi ? A0 : B0, s1 = hi ? A1 : B1;
            int e0 = __shfl_xor(s0, 32), e1 = __shfl_xor(s1, 32);
            i32x4 wv;
            wv[0] = hi ? e0 : A0;
            wv[1] = hi ? e1 : A1;
            wv[2] = hi ? B0 : e0;
            wv[3] = hi ? B1 : e1;
            bf16x8 pa = __builtin_bit_cast(bf16x8, wv);
            const int co = 64 * h + 32 * s + 16 * hi;   // kv byte offset
            bf16x8 v0 = *(const bf16x8*)(VsC + l31 * 128 + (co ^ sw0));
            bf16x8 v1 = *(const bf16x8*)(VsC + (32 + l31) * 128 + (co ^ sw0));
            o0 = __builtin_amdgcn_mfma_f32_32x32x16_bf16(pa, v0, o0, 0, 0, 0);
            o1 = __builtin_amdgcn_mfma_f32_32x32x16_bf16(pa, v1, o1, 0, 0, 0);
          }
          __builtin_amdgcn_s_setprio(0);
        }
      }
    }
    SB0;   // pin this tile's LDS reads above next iteration's barrier
    cur ^= 1;
  }

  // epilogue: combine lane-halves' row-sums, normalize + store
  float linv = 1.f / (lsum + __shfl_xor(lsum, 32));
#pragma unroll
  for (int r = 0; r < 16; ++r) {
    const int crow = (r & 3) + 8 * (r >> 2) + 4 * hi;
    float ir = __shfl(linv, crow);
    const int qrow = qw + crow;
    __bf16* yp = Y + ((size_t)(b_ * TT + qrow)) * CC + h_ * HD + l31;
    yp[0]  = (__bf16)(o0[r] * ir);
    yp[32] = (__bf16)(o1[r] * ir);
  }
}

// ---------------- launch ----------------
extern "C" void kernel_launch(void* const* d_in, const int* in_sizes, int n_in,
                              void* d_out, int out_size, void* d_ws, size_t ws_size,
                              hipStream_t stream) {
  (void)in_sizes; (void)n_in; (void)out_size; (void)ws_size;
  const float* x  = (const float*)d_in[0];
  const float* Wk = (const float*)d_in[1];
  const float* bk = (const float*)d_in[2];
  const float* Wq = (const float*)d_in[3];
  const float* bq = (const float*)d_in[4];
  const float* Wv = (const float*)d_in[5];
  const float* bv = (const float*)d_in[6];
  const float* Wp = (const float*)d_in[7];
  const float* bp = (const float*)d_in[8];
  const int* pmask = (const int*)d_in[9];

  char* ws = (char*)d_ws;
  const size_t MB = 1024 * 1024;
  __bf16* xb   = (__bf16*)(ws);            // 16MB; reused as attn-out y
  __bf16* wqkv = (__bf16*)(ws + 16 * MB);  // 6MB  [3072][1024] (q,k,v concat)
  __bf16* wpb  = (__bf16*)(ws + 22 * MB);  // 2MB
  __bf16* qb   = (__bf16*)(ws + 24 * MB);  // 16MB [B,H,T,HD]
  __bf16* kb   = qb + ((size_t)1 << 23);   // 16MB @40MB
  __bf16* vtb  = (__bf16*)(ws + 56 * MB);  // 16MB [B,H,HD,T] (written by gemm_qkv)
  __bf16* yb   = xb;                       // attn out overwrites x

  int n4 = (MM * CC) / 4;                  // 2097152
  cvt_f32_bf16<<<(n4 + 255) / 256, 256, 0, stream>>>(x, xb, n4);
  cvt_w4<<<dim3((CC * CC / 4) / 256, 4), 256, 0, stream>>>(
      Wq, Wk, Wv, Wp, wqkv, wpb);

  // fused QKV projection + V-transpose epilogue (128x128 tiles, grid 1536)
  gemm_qkv<<<(MM / 128) * (3 * CC / 128), 256, 0, stream>>>(
      xb, wqkv, bq, bk, bv, qb, vtb);

  attn_fwd<<<NQT2 * BB * HH, 256, 0, stream>>>(qb, kb, vtb, pmask, yb);

  gemm_proj<<<(MM / 128) * (CC / 128), 256, 0, stream>>>(
      yb, wpb, bp, (float*)d_out, MM, CC, CC);
}

// Round 12
// 170.171 us; speedup vs baseline: 2.7964x; 1.0262x over previous
//
#include <hip/hip_runtime.h>
#include <hip/hip_bf16.h>
#include <math.h>
#include <stdint.h>

// Problem constants (reference: B=4, T=2048, C=1024, H=16, HD=64)
#define BB 4
#define TT 2048
#define CC 1024
#define HH 16
#define HD 64
#define MM (BB*TT)   // 8192
#define NQT2 16      // T / 128 q-tiles for attention (QBLK=128)
#define SCQ 0.180336878f   // (1/sqrt(HD)) * log2(e): Q pre-scale for exp2-domain softmax

using f32x2  = __attribute__((ext_vector_type(2))) float;
using f32x4  = __attribute__((ext_vector_type(4))) float;
using f32x16 = __attribute__((ext_vector_type(16))) float;
using i32x4  = __attribute__((ext_vector_type(4))) int;
using bf16x4 = __attribute__((ext_vector_type(4))) __bf16;
using bf16x8 = __attribute__((ext_vector_type(8))) __bf16;

__device__ __forceinline__ float fast_exp2(float x) {
  return __builtin_amdgcn_exp2f(x);   // v_exp_f32 (native exp2 on gfx950)
}

__device__ __forceinline__ int cvt_pk_bf16(float lo, float hi_) {
  int r;
  asm("v_cvt_pk_bf16_f32 %0, %1, %2" : "=v"(r) : "v"(lo), "v"(hi_));
  return r;   // low 16 = bf16(lo), high 16 = bf16(hi_)
}

__device__ __forceinline__ f32x2 max2(f32x2 a, f32x2 b) {
  return __builtin_elementwise_max(a, b);   // v_pk_max_f32
}

__device__ __forceinline__ void gload_lds16(const void* g, void* l) {
  __builtin_amdgcn_global_load_lds(
      (__attribute__((address_space(1))) void*)(void*)(g),
      (__attribute__((address_space(3))) void*)(l), 16, 0, 0);
}

// ---------------- fp32 -> bf16 converts ----------------
__global__ __launch_bounds__(256)
void cvt_f32_bf16(const float* __restrict__ s, __bf16* __restrict__ d, int n4) {
  int i = blockIdx.x * 256 + threadIdx.x;
  if (i >= n4) return;
  float4 v = ((const float4*)s)[i];
  bf16x4 o;
  o[0] = (__bf16)v.x; o[1] = (__bf16)v.y; o[2] = (__bf16)v.z; o[3] = (__bf16)v.w;
  *(bf16x4*)(d + (size_t)i * 4) = o;
}

// 4 weights in one launch; Wq scaled by SCQ and Wq/Wk/Wv written into the
// contiguous [3072][1024] concat buffer (order q,k,v); Wp separate.
__global__ __launch_bounds__(256)
void cvt_w4(const float* __restrict__ Wq, const float* __restrict__ Wk,
            const float* __restrict__ Wv, const float* __restrict__ Wp,
            __bf16* __restrict__ wqkv, __bf16* __restrict__ wpb) {
  int which = blockIdx.y;
  const float* s = which == 0 ? Wq : which == 1 ? Wk : which == 2 ? Wv : Wp;
  __bf16* d = which == 3 ? wpb : wqkv + (size_t)which * CC * CC;
  float sc = which == 0 ? SCQ : 1.f;
  int i = blockIdx.x * 256 + threadIdx.x;   // grid.x = (CC*CC/4)/256 = 1024
  float4 v = ((const float4*)s)[i];
  bf16x4 o;
  o[0] = (__bf16)(v.x * sc); o[1] = (__bf16)(v.y * sc);
  o[2] = (__bf16)(v.z * sc); o[3] = (__bf16)(v.w * sc);
  *(bf16x4*)(d + (size_t)i * 4) = o;
}

#define WAITV0 asm volatile("s_waitcnt vmcnt(0)" ::: "memory")
#define BARR   __builtin_amdgcn_s_barrier()
#define SB0    __builtin_amdgcn_sched_barrier(0)

// ==== QKV GEMM v12: r11 skeleton + stage-1-ahead DOUBLE BUFFER ==============
// C[8192,3072] = A[8192,1024] x Wqkv[3072,1024]^T + bias.
// r11 post-mortem: conflicts 0, multi-block OK, yet 80us — the invariant
// across all variants was ZERO intra-block overlap: every K-step exposed the
// full vmem latency (sync -> load -> vmcnt(0) -> compute). v12 adds the
// attn-v6-proven pipeline: prologue stage(0); per iter WAITV0 (own stage(t),
// issued one compute phase earlier -> latency hidden) ; BARR ; issue
// stage(t+1) into buf^1 (WAR-safe: buf^1 readers passed this barrier) ;
// ds_read+MFMA on buf[cur]. One barrier per K-step. LDS 32.8KB (2x dbuf);
// lt transpose buffer aliases (barrier first). Slot-swizzle staging/read
// pair kept (r10-numerics + r11-counter proven, conflicts = 0).
// proj 0/1 (Q,K): bf16 head-split store; proj 2 (V): 2x 64-col LDS transpose
// chunks -> Vt[bh][d][t].
__global__ __launch_bounds__(256, 2)
void gemm_qkv(const __bf16* __restrict__ A, const __bf16* __restrict__ Bm,
              const float* __restrict__ b0, const float* __restrict__ b1,
              const float* __restrict__ b2, __bf16* __restrict__ out,
              __bf16* __restrict__ vt) {
  __shared__ __bf16 U[16384];        // 32KB: As[2][4096] + Bs[2][4096]; lt alias
  char* Ub = (char*)U;               // A buf b at b*8192; B buf b at 16384+b*8192
  const int tid = threadIdx.x;
  const int wid = tid >> 6, lane = tid & 63;
  const int g = lane >> 4, lq = lane & 15;
  // XCD-chunk swizzle: 1536 blocks = 8 XCDs x 192 contiguous logicals
  const int bx0 = blockIdx.x;
  const int bx = (bx0 & 7) * 192 + (bx0 >> 3);
  const int bm = bx / 24, bn = bx % 24;
  const int brow = bm << 7, bcol = bn << 7;
  const int wr = (wid >> 1) << 6, wc = (wid & 1) << 6;

  // staging: thread handles chunks c0=tid, c1=tid+256 per array (16B each).
  // chunk c -> LDS row c>>2, slot c&3 (linear dest); global source column is
  // inverse-swizzled so read-side slot=(g+(row>>1))&3 recovers K-chunk g.
  const int c0 = tid, c1 = tid + 256;
  const int r0 = c0 >> 2, s0_ = (((c0 & 3) - (r0 >> 1)) & 3) << 4;
  const int r1 = c1 >> 2, s1_ = (((c1 & 3) - (r1 >> 1)) & 3) << 4;
  const char* Ag = (const char*)A;
  const char* Bg = (const char*)Bm;

#define STAGEQ(ko, buf)                                                       \
  {                                                                           \
    gload_lds16(Ag + (size_t)(brow + r0) * 2048 + (ko) + s0_,                 \
                Ub + (buf) * 8192 + c0 * 16);                                 \
    gload_lds16(Ag + (size_t)(brow + r1) * 2048 + (ko) + s1_,                 \
                Ub + (buf) * 8192 + c1 * 16);                                 \
    gload_lds16(Bg + (size_t)(bcol + r0) * 2048 + (ko) + s0_,                 \
                Ub + 16384 + (buf) * 8192 + c0 * 16);                         \
    gload_lds16(Bg + (size_t)(bcol + r1) * 2048 + (ko) + s1_,                 \
                Ub + 16384 + (buf) * 8192 + c1 * 16);                         \
  }

  f32x4 acc[4][4] = {};

  STAGEQ(0, 0);                      // prologue: K-step 0 into buf 0
  int cur = 0;
#pragma unroll 1
  for (int t = 0; t < 32; ++t) {
    WAITV0; BARR; SB0;               // stage(t) landed; buf^1 readers done
    if (t + 1 < 32) STAGEQ((t + 1) << 6, cur ^ 1);
    const char* Ac = Ub + cur * 8192;
    const char* Bc = Ub + 16384 + cur * 8192;
    bf16x8 av[4], bv[4];
#pragma unroll
    for (int m = 0; m < 4; ++m) {
      int row = wr + m * 16 + lq;
      int sl = (g + (row >> 1)) & 3;
      av[m] = *(const bf16x8*)(Ac + row * 64 + sl * 16);
    }
#pragma unroll
    for (int n = 0; n < 4; ++n) {
      int row = wc + n * 16 + lq;
      int sl = (g + (row >> 1)) & 3;
      bv[n] = *(const bf16x8*)(Bc + row * 64 + sl * 16);
    }
#pragma unroll
    for (int m = 0; m < 4; ++m)
#pragma unroll
      for (int n = 0; n < 4; ++n)
        acc[m][n] = __builtin_amdgcn_mfma_f32_16x16x32_bf16(av[m], bv[n], acc[m][n], 0, 0, 0);
    SB0;
    cur ^= 1;
  }
#undef STAGEQ

  const int proj = bn >> 3;   // uniform per block (8 x 128 = 1024 cols / proj)
  if (proj < 2) {
    // epilogue: bias + bf16 head-split store [proj][B,H,T,HD]
    const float* bias = proj == 0 ? b0 : b1;
    const float bsc = proj == 0 ? SCQ : 1.f;
#pragma unroll
    for (int n = 0; n < 4; ++n) {
      int col = bcol + wc + n * 16 + lq;
      int cw = col & (CC - 1);
      float bb = bias[cw] * bsc;
      int h_ = cw >> 6, d_ = cw & (HD - 1);
#pragma unroll
      for (int m = 0; m < 4; ++m) {
        int row0 = brow + wr + m * 16 + g * 4;
#pragma unroll
        for (int i = 0; i < 4; ++i) {
          int row = row0 + i;
          int b_ = row >> 11, t_ = row & (TT - 1);
          out[((size_t)proj << 23) +
              ((((size_t)b_ * HH + h_) * TT + t_) << 6) + d_] =
              (__bf16)(acc[m][n][i] + bb);
        }
      }
    }
  } else {
    // V: transpose 128x128 tile through lt (2 chunks of 64 cols = 1 head
    // each) -> Vt[bh][d][t] coalesced. lt ALIASES As/Bs: barrier first.
    __syncthreads();                             // all K-loop LDS reads done
    __bf16* lt = U;                              // [64 cols][130 rows]
    const int cv0 = (bn & 7) << 7;               // col offset within V region
    const int b_ = brow >> 11, t0 = brow & (TT - 1);
    const int hbase = (bn & 7) << 1;
    const int rd_d = tid >> 2, rd_tb = (tid & 3) << 5;   // 64 d x 128 t
#pragma unroll
    for (int cc = 0; cc < 2; ++cc) {
      if ((wid & 1) == cc) {                     // 2 writer waves per chunk
#pragma unroll
        for (int n = 0; n < 4; ++n) {
          int c = (n << 4) + lq;                 // 0..63 within chunk
          float bb = b2[cv0 + (cc << 6) + c];
#pragma unroll
          for (int m = 0; m < 4; ++m) {
            int r = wr + (m << 4) + (g << 2);    // 0..127 over both writers
            bf16x4 pk;
#pragma unroll
            for (int i = 0; i < 4; ++i)
              pk[i] = (__bf16)(acc[m][n][i] + bb);
            *(bf16x4*)(lt + c * 130 + r) = pk;
          }
        }
      }
      __syncthreads();
      // readers: all 256 threads; d = tid>>2, 32 t-elems each
      __bf16* dst = vt + (((size_t)((b_ * HH + hbase + cc) * HD + rd_d)) << 11)
                       + t0 + rd_tb;
      const __bf16* srcl = lt + rd_d * 130 + rd_tb;
#pragma unroll
      for (int j = 0; j < 4; ++j)
        *(bf16x8*)(dst + j * 8) = *(const bf16x8*)(srcl + j * 8);
      __syncthreads();
    }
  }
}

// ==== proj GEMM v12: same double-buffered pipeline, fp32 out ================
__global__ __launch_bounds__(256, 2)
void gemm_proj(const __bf16* __restrict__ A, const __bf16* __restrict__ Bm,
               const float* __restrict__ bias, float* __restrict__ out) {
  __shared__ __bf16 U[16384];        // 32KB: As[2][4096] + Bs[2][4096]
  char* Ub = (char*)U;
  const int tid = threadIdx.x;
  const int wid = tid >> 6, lane = tid & 63;
  const int g = lane >> 4, lq = lane & 15;
  // XCD-chunk swizzle: 512 blocks = 8 XCDs x 64 contiguous logicals
  const int bx0 = blockIdx.x;
  const int bx = (bx0 & 7) * 64 + (bx0 >> 3);
  const int brow = (bx >> 3) << 7;         // 64 bm
  const int bcol = (bx & 7) << 7;          // 8 bn
  const int wr = (wid >> 1) << 6, wc = (wid & 1) << 6;

  const int c0 = tid, c1 = tid + 256;
  const int r0 = c0 >> 2, s0_ = (((c0 & 3) - (r0 >> 1)) & 3) << 4;
  const int r1 = c1 >> 2, s1_ = (((c1 & 3) - (r1 >> 1)) & 3) << 4;
  const char* Ag = (const char*)A;
  const char* Bg = (const char*)Bm;

#define STAGEP(ko, buf)                                                       \
  {                                                                           \
    gload_lds16(Ag + (size_t)(brow + r0) * 2048 + (ko) + s0_,                 \
                Ub + (buf) * 8192 + c0 * 16);                                 \
    gload_lds16(Ag + (size_t)(brow + r1) * 2048 + (ko) + s1_,                 \
                Ub + (buf) * 8192 + c1 * 16);                                 \
    gload_lds16(Bg + (size_t)(bcol + r0) * 2048 + (ko) + s0_,                 \
                Ub + 16384 + (buf) * 8192 + c0 * 16);                         \
    gload_lds16(Bg + (size_t)(bcol + r1) * 2048 + (ko) + s1_,                 \
                Ub + 16384 + (buf) * 8192 + c1 * 16);                         \
  }

  f32x4 acc[4][4] = {};

  STAGEP(0, 0);
  int cur = 0;
#pragma unroll 1
  for (int t = 0; t < 32; ++t) {
    WAITV0; BARR; SB0;
    if (t + 1 < 32) STAGEP((t + 1) << 6, cur ^ 1);
    const char* Ac = Ub + cur * 8192;
    const char* Bc = Ub + 16384 + cur * 8192;
    bf16x8 av[4], bv[4];
#pragma unroll
    for (int m = 0; m < 4; ++m) {
      int row = wr + m * 16 + lq;
      int sl = (g + (row >> 1)) & 3;
      av[m] = *(const bf16x8*)(Ac + row * 64 + sl * 16);
    }
#pragma unroll
    for (int n = 0; n < 4; ++n) {
      int row = wc + n * 16 + lq;
      int sl = (g + (row >> 1)) & 3;
      bv[n] = *(const bf16x8*)(Bc + row * 64 + sl * 16);
    }
#pragma unroll
    for (int m = 0; m < 4; ++m)
#pragma unroll
      for (int n = 0; n < 4; ++n)
        acc[m][n] = __builtin_amdgcn_mfma_f32_16x16x32_bf16(av[m], bv[n], acc[m][n], 0, 0, 0);
    SB0;
    cur ^= 1;
  }
#undef STAGEP

#pragma unroll
  for (int m = 0; m < 4; ++m) {
#pragma unroll
    for (int n = 0; n < 4; ++n) {
      int col = bcol + wc + n * 16 + lq;
      float bb = bias[col];
      int row0 = brow + wr + m * 16 + g * 4;
#pragma unroll
      for (int i = 0; i < 4; ++i)
        out[(size_t)(row0 + i) * CC + col] = acc[m][n][i] + bb;
    }
  }
}

// ---------------- Flash attention v6 (causal + padding mask) ----------------
// grid 1024 = 16 q-tiles x 64 bh, 256 threads = 4 waves x 32 q-rows (QBLK=128).
// 32x32x16 MFMA, swapped QK^T, split-half S, in-register softmax.
// Full-grid residency: double-buffered K/V (32.8KB LDS) + launch_bounds(256,4)
// -> 4 blocks/CU -> all 1024 blocks co-resident. Heavy-first Latin-square qi
// map balances per-CU work. One barrier per tile, counted staging.
// C/D layout (m74/m101): col = lane&31, row = (r&3) + 8*(r>>2) + 4*(lane>>5).
__global__ __launch_bounds__(256, 4)
void attn_fwd(const __bf16* __restrict__ Q, const __bf16* __restrict__ K,
              const __bf16* __restrict__ Vt, const int* __restrict__ pm,
              __bf16* __restrict__ Y) {
  __shared__ __bf16 Ks[2][64 * 64];   // 16 KiB
  __shared__ __bf16 Vs[2][64 * 64];   // 16 KiB
  __shared__ int flg;
  const int tid = threadIdx.x, wid = tid >> 6, lane = tid & 63;
  const int l31 = lane & 31, hi = lane >> 5;
  const int bx = blockIdx.x;
  const int bh = bx & 63, jj = bx >> 6;          // jj 0..15
  const int qi = 15 - (4 * (jj >> 2) + ((jj + (jj >> 2)) & 3));
  const int b_ = bh >> 4, h_ = bh & 15;
  const __bf16* Qb = Q + (size_t)bh * TT * HD;
  const __bf16* Kb = K + (size_t)bh * TT * HD;
  const __bf16* Vb = Vt + (size_t)bh * HD * TT;
  const int* pmb = pm + b_ * TT;

  const int so = tid * 16;                 // 16B chunk, 0..4080
  const int srow = tid >> 3;               // 0..31
  const int scol = (so & 127) ^ ((srow & 7) << 4);   // inverse-swizzled src col

  const int q0 = qi << 7;
  const int qw = q0 + wid * 32;            // this wave's 32 q-rows
  const int ntiles = 2 * qi + 2;           // >= 2 always
  const int sw0 = (l31 & 7) << 4;

  // Q fragments: lane holds Q[qw+l31][16s + 8hi .. +7], s=0..3
  bf16x8 qf[4];
#pragma unroll
  for (int s = 0; s < 4; ++s)
    qf[s] = *(const bf16x8*)(Qb + (size_t)(qw + l31) * HD + s * 16 + hi * 8);
  SB0;   // pin qf loads above the staging issues (vmcnt accounting)

  // padding-mask block check: 256 threads x 2 int4 cover the 2048-int pm row
  int4 pa4 = ((const int4*)pmb)[tid];
  int4 pb4 = ((const int4*)pmb)[tid + 256];
  bool okp = pa4.x && pa4.y && pa4.z && pa4.w &&
             pb4.x && pb4.y && pb4.z && pb4.w;
  if (tid == 0) flg = 1;
  __syncthreads();
  if (!okp) flg = 0;                       // benign race (all writers store 0)

  // prologue: stage tile 0 into buf 0 (4 gloads: 2 K + 2 V)
  {
    char* kd = (char*)&Ks[0][0] + so;
    char* vd = (char*)&Vs[0][0] + so;
#pragma unroll
    for (int j = 0; j < 2; ++j) {
      gload_lds16((const char*)Kb + (size_t)(srow + 32 * j) * 128 + scol,
                  kd + j * 4096);
      gload_lds16((const char*)Vb + (size_t)(srow + 32 * j) * (TT * 2) + scol,
                  vd + j * 4096);
    }
  }
  __syncthreads();                         // tile 0 staged everywhere; flg final
  const bool allones = (flg != 0);

  f32x16 o0 = {}, o1 = {};                 // O[q=crow(r,hi)][d = l31 | 32+l31]
  f32x16 vzero = {};                       // persistent zero C-operand
  float lsum = 0.f;                        // partial row-sum (this lane-half)
  float m = -INFINITY;                     // running max for q = qw+l31

  int cur = 0;
#pragma unroll 1
  for (int t = 0; t < ntiles; ++t) {
    const int kv0 = t << 6;
    // ---- own stage(t) done (issued a full compute phase ago -> cheap) ----
    WAITV0;
    __builtin_amdgcn_s_barrier(); SB0;  // tile t staged AND t-1 reads done
    // ---- issue stage(t+1) into buf[cur^1] (tile t-1's slot, now free) ----
    if (t + 1 < ntiles) {
      char* kd = (char*)&Ks[0][0] + (cur ^ 1) * 8192 + so;
      char* vd = (char*)&Vs[0][0] + (cur ^ 1) * 8192 + so;
      const size_t nk = (size_t)(kv0 + 64);
#pragma unroll
      for (int j = 0; j < 2; ++j) {
        gload_lds16((const char*)Kb + (nk + srow + 32 * j) * 128 + scol,
                    kd + j * 4096);
        gload_lds16((const char*)Vb + (size_t)(srow + 32 * j) * (TT * 2) +
                        nk * 2 + scol,
                    vd + j * 4096);
      }
    }

    unsigned long long bits = ~0ull;
    if (__builtin_expect(!allones, 0))     // rare slow path
      bits = __ballot(pmb[kv0 + lane] != 0);

    if (kv0 <= qw + 31) {                  // wave-uniform participation
      const char* VsC = (const char*)&Vs[0][0] + cur * 8192;

#pragma unroll
      for (int h = 0; h < 2; ++h) {
        const int kvh = kv0 + 32 * h;
        if (kvh <= qw + 31) {              // wave-uniform per-half gate
          // ---- QK^T (swapped): S[kvh+crow][q=l31] ----
          const char* KsC =
              (const char*)&Ks[0][0] + cur * 8192 + (32 * h + l31) * 128;
          f32x16 S;
          __builtin_amdgcn_s_setprio(1);
          {
            bf16x8 k0 = *(const bf16x8*)(KsC + ((16 * hi) ^ sw0));
            S = __builtin_amdgcn_mfma_f32_32x32x16_bf16(k0, qf[0], vzero, 0, 0, 0);
          }
#pragma unroll
          for (int s = 1; s < 4; ++s) {
            bf16x8 kf = *(const bf16x8*)(KsC + ((32 * s + 16 * hi) ^ sw0));
            S = __builtin_amdgcn_mfma_f32_32x32x16_bf16(kf, qf[s], S, 0, 0, 0);
          }
          __builtin_amdgcn_s_setprio(0);

          // ---- masks ----
          if (__builtin_expect(bits != ~0ull, 0)) {   // padding (rare)
#pragma unroll
            for (int r = 0; r < 16; ++r) {
              const int c = (r & 3) + 8 * (r >> 2);
              if (!((bits >> (32 * h + c + 4 * hi)) & 1ull)) S[r] = -INFINITY;
            }
          }
          if (kvh + 31 > qw) {             // causal diag (wave-uniform)
            const int thr = qw + l31 - kvh - 4 * hi;
#pragma unroll
            for (int r = 0; r < 16; ++r) {
              const int c = (r & 3) + 8 * (r >> 2);
              S[r] = (c <= thr) ? S[r] : -INFINITY;
            }
          }

          // ---- row max via packed-f32 tree + defer-rescale check ----
          f32x2 x0 = {S[0], S[1]},  x1 = {S[2], S[3]};
          f32x2 x2 = {S[4], S[5]},  x3 = {S[6], S[7]};
          f32x2 x4 = {S[8], S[9]},  x5 = {S[10], S[11]};
          f32x2 x6 = {S[12], S[13]}, x7 = {S[14], S[15]};
          x0 = max2(x0, x4); x1 = max2(x1, x5);
          x2 = max2(x2, x6); x3 = max2(x3, x7);
          x0 = max2(x0, x2); x1 = max2(x1, x3);
          x0 = max2(x0, x1);
          float pmax = fmaxf(x0[0], x0[1]);
          if (!__all(pmax <= m + 8.f)) {
            float nm = fmaxf(pmax, __shfl_xor(pmax, 32));  // full row max
            float mn = fmaxf(m, nm);
            float c = fast_exp2(m - mn);
            m = mn;
            lsum *= c;
#pragma unroll
            for (int r = 0; r < 16; ++r) {
              float cr = __shfl(c, (r & 3) + 8 * (r >> 2) + 4 * hi);
              o0[r] *= cr;
              o1[r] *= cr;
            }
          }

          // ---- P = exp2(S - m) (packed sub, trans exp) ----
          const f32x2 mm = {m, m};
#pragma unroll
          for (int r = 0; r < 16; r += 2) {
            f32x2 u = {S[r], S[r + 1]};
            u -= mm;                      // v_pk_add_f32
            S[r] = fast_exp2(u[0]);
            S[r + 1] = fast_exp2(u[1]);
          }
          // ---- in-lane row-sum via packed-f32 tree ----
          {
            f32x2 u0 = {S[0], S[1]},  u1 = {S[2], S[3]};
            f32x2 u2 = {S[4], S[5]},  u3 = {S[6], S[7]};
            f32x2 u4 = {S[8], S[9]},  u5 = {S[10], S[11]};
            f32x2 u6 = {S[12], S[13]}, u7 = {S[14], S[15]};
            u0 += u4; u1 += u5; u2 += u6; u3 += u7;
            u0 += u2; u1 += u3;
            u0 += u1;
            lsum += u0[0] + u0[1];
          }

          // ---- PV: build A-fragments (validated select+shfl_xor exchange) ----
          __builtin_amdgcn_s_setprio(1);
#pragma unroll
          for (int s = 0; s < 2; ++s) {
            int A0 = cvt_pk_bf16(S[8 * s + 0], S[8 * s + 1]);
            int A1 = cvt_pk_bf16(S[8 * s + 2], S[8 * s + 3]);
            int B0 = cvt_pk_bf16(S[8 * s + 4], S[8 * s + 5]);
            int B1 = cvt_pk_bf16(S[8 * s + 6], S[8 * s + 7]);
            // exchange across lane+-32: lo lanes need A-pairs of BOTH halves,
            // hi lanes need B-pairs of BOTH halves.
            int s0 = hi ? A0 : B0, s1 = hi ? A1 : B1;
            int e0 = __shfl_xor(s0, 32), e1 = __shfl_xor(s1, 32);
            i32x4 wv;
            wv[0] = hi ? e0 : A0;
            wv[1] = hi ? e1 : A1;
            wv[2] = hi ? B0 : e0;
            wv[3] = hi ? B1 : e1;
            bf16x8 pa = __builtin_bit_cast(bf16x8, wv);
            const int co = 64 * h + 32 * s + 16 * hi;   // kv byte offset
            bf16x8 v0 = *(const bf16x8*)(VsC + l31 * 128 + (co ^ sw0));
            bf16x8 v1 = *(const bf16x8*)(VsC + (32 + l31) * 128 + (co ^ sw0));
            o0 = __builtin_amdgcn_mfma_f32_32x32x16_bf16(pa, v0, o0, 0, 0, 0);
            o1 = __builtin_amdgcn_mfma_f32_32x32x16_bf16(pa, v1, o1, 0, 0, 0);
          }
          __builtin_amdgcn_s_setprio(0);
        }
      }
    }
    SB0;   // pin this tile's LDS reads above next iteration's barrier
    cur ^= 1;
  }

  // epilogue: combine lane-halves' row-sums, normalize + store
  float linv = 1.f / (lsum + __shfl_xor(lsum, 32));
#pragma unroll
  for (int r = 0; r < 16; ++r) {
    const int crow = (r & 3) + 8 * (r >> 2) + 4 * hi;
    float ir = __shfl(linv, crow);
    const int qrow = qw + crow;
    __bf16* yp = Y + ((size_t)(b_ * TT + qrow)) * CC + h_ * HD + l31;
    yp[0]  = (__bf16)(o0[r] * ir);
    yp[32] = (__bf16)(o1[r] * ir);
  }
}

// ---------------- launch ----------------
extern "C" void kernel_launch(void* const* d_in, const int* in_sizes, int n_in,
                              void* d_out, int out_size, void* d_ws, size_t ws_size,
                              hipStream_t stream) {
  (void)in_sizes; (void)n_in; (void)out_size; (void)ws_size;
  const float* x  = (const float*)d_in[0];
  const float* Wk = (const float*)d_in[1];
  const float* bk = (const float*)d_in[2];
  const float* Wq = (const float*)d_in[3];
  const float* bq = (const float*)d_in[4];
  const float* Wv = (const float*)d_in[5];
  const float* bv = (const float*)d_in[6];
  const float* Wp = (const float*)d_in[7];
  const float* bp = (const float*)d_in[8];
  const int* pmask = (const int*)d_in[9];

  char* ws = (char*)d_ws;
  const size_t MB = 1024 * 1024;
  __bf16* xb   = (__bf16*)(ws);            // 16MB; reused as attn-out y
  __bf16* wqkv = (__bf16*)(ws + 16 * MB);  // 6MB  [3072][1024] (q,k,v concat)
  __bf16* wpb  = (__bf16*)(ws + 22 * MB);  // 2MB
  __bf16* qb   = (__bf16*)(ws + 24 * MB);  // 16MB [B,H,T,HD]
  __bf16* kb   = qb + ((size_t)1 << 23);   // 16MB @40MB
  __bf16* vtb  = (__bf16*)(ws + 56 * MB);  // 16MB [B,H,HD,T] (written by gemm_qkv)
  __bf16* yb   = xb;                       // attn out overwrites x

  int n4 = (MM * CC) / 4;                  // 2097152
  cvt_f32_bf16<<<(n4 + 255) / 256, 256, 0, stream>>>(x, xb, n4);
  cvt_w4<<<dim3((CC * CC / 4) / 256, 4), 256, 0, stream>>>(
      Wq, Wk, Wv, Wp, wqkv, wpb);

  // fused QKV projection + V-transpose epilogue (128x128 tiles, grid 1536)
  gemm_qkv<<<(MM / 128) * (3 * CC / 128), 256, 0, stream>>>(
      xb, wqkv, bq, bk, bv, qb, vtb);

  attn_fwd<<<NQT2 * BB * HH, 256, 0, stream>>>(qb, kb, vtb, pmask, yb);

  gemm_proj<<<(MM / 128) * (CC / 128), 256, 0, stream>>>(
      yb, wpb, bp, (float*)d_out);
}

// Round 13
// 168.867 us; speedup vs baseline: 2.8180x; 1.0077x over previous
//
#include <hip/hip_runtime.h>
#include <hip/hip_bf16.h>
#include <math.h>
#include <stdint.h>

// Problem constants (reference: B=4, T=2048, C=1024, H=16, HD=64)
#define BB 4
#define TT 2048
#define CC 1024
#define HH 16
#define HD 64
#define MM (BB*TT)   // 8192
#define NQT2 16      // T / 128 q-tiles for attention (QBLK=128)
#define SCQ 0.180336878f   // (1/sqrt(HD)) * log2(e): Q pre-scale for exp2-domain softmax

using f32x2  = __attribute__((ext_vector_type(2))) float;
using f32x4  = __attribute__((ext_vector_type(4))) float;
using f32x16 = __attribute__((ext_vector_type(16))) float;
using i32x4  = __attribute__((ext_vector_type(4))) int;
using bf16x4 = __attribute__((ext_vector_type(4))) __bf16;
using bf16x8 = __attribute__((ext_vector_type(8))) __bf16;

__device__ __forceinline__ float fast_exp2(float x) {
  return __builtin_amdgcn_exp2f(x);   // v_exp_f32 (native exp2 on gfx950)
}

__device__ __forceinline__ int cvt_pk_bf16(float lo, float hi_) {
  int r;
  asm("v_cvt_pk_bf16_f32 %0, %1, %2" : "=v"(r) : "v"(lo), "v"(hi_));
  return r;   // low 16 = bf16(lo), high 16 = bf16(hi_)
}

__device__ __forceinline__ f32x2 max2(f32x2 a, f32x2 b) {
  return __builtin_elementwise_max(a, b);   // v_pk_max_f32
}

__device__ __forceinline__ void gload_lds16(const void* g, void* l) {
  __builtin_amdgcn_global_load_lds(
      (__attribute__((address_space(1))) void*)(void*)(g),
      (__attribute__((address_space(3))) void*)(l), 16, 0, 0);
}

// ---------------- fp32 -> bf16 converts ----------------
__global__ __launch_bounds__(256)
void cvt_f32_bf16(const float* __restrict__ s, __bf16* __restrict__ d, int n4) {
  int i = blockIdx.x * 256 + threadIdx.x;
  if (i >= n4) return;
  float4 v = ((const float4*)s)[i];
  bf16x4 o;
  o[0] = (__bf16)v.x; o[1] = (__bf16)v.y; o[2] = (__bf16)v.z; o[3] = (__bf16)v.w;
  *(bf16x4*)(d + (size_t)i * 4) = o;
}

// 4 weights in one launch; Wq scaled by SCQ and Wq/Wk/Wv written into the
// contiguous [3072][1024] concat buffer (order q,k,v); Wp separate.
__global__ __launch_bounds__(256)
void cvt_w4(const float* __restrict__ Wq, const float* __restrict__ Wk,
            const float* __restrict__ Wv, const float* __restrict__ Wp,
            __bf16* __restrict__ wqkv, __bf16* __restrict__ wpb) {
  int which = blockIdx.y;
  const float* s = which == 0 ? Wq : which == 1 ? Wk : which == 2 ? Wv : Wp;
  __bf16* d = which == 3 ? wpb : wqkv + (size_t)which * CC * CC;
  float sc = which == 0 ? SCQ : 1.f;
  int i = blockIdx.x * 256 + threadIdx.x;   // grid.x = (CC*CC/4)/256 = 1024
  float4 v = ((const float4*)s)[i];
  bf16x4 o;
  o[0] = (__bf16)(v.x * sc); o[1] = (__bf16)(v.y * sc);
  o[2] = (__bf16)(v.z * sc); o[3] = (__bf16)(v.w * sc);
  *(bf16x4*)(d + (size_t)i * 4) = o;
}

#define WAITV4 asm volatile("s_waitcnt vmcnt(4)" ::: "memory")
#define WAITV0 asm volatile("s_waitcnt vmcnt(0)" ::: "memory")
#define BARR   __builtin_amdgcn_s_barrier()
#define SB0    __builtin_amdgcn_sched_barrier(0)

// ==== QKV GEMM v13: r12 skeleton + TRIPLE buffer (prefetch distance 2) ======
// C[8192,3072] = A[8192,1024] x Wqkv[3072,1024]^T + bias.
// r12 post-mortem: single-step prefetch left ~300-500 cy/iter of exposed vmem
// latency (compute phase ~300 cy < load latency ~500-900 cy). v13 gives each
// stage TWO compute phases of cover: prologue stages k0,k1 (8 outstanding);
// per iter: WAITV4 (drain oldest 4 = stage(t); stage(t+1) stays in flight);
// BARR (stage(t) visible everywhere; buf[(t+2)%3] readers done at t-1);
// issue stage(t+2) into buf[(t+2)%3]; compute buf[t%3]. vmcnt never 0 in
// steady state (T4). LDS 48KB (3 bufs x 8KB x 2 operands) -> 3 blocks/CU.
// Slot-swizzle staging/read kept (conflicts measured 0 in r11/r12).
// proj 0/1 (Q,K): bf16 head-split store; proj 2 (V): 2x 64-col LDS transpose
// chunks -> Vt[bh][d][t] (lt aliases buffers; barrier first).
__global__ __launch_bounds__(256, 2)
void gemm_qkv(const __bf16* __restrict__ A, const __bf16* __restrict__ Bm,
              const float* __restrict__ b0, const float* __restrict__ b1,
              const float* __restrict__ b2, __bf16* __restrict__ out,
              __bf16* __restrict__ vt) {
  __shared__ __bf16 U[24576];        // 48KB: A bufs 0..2 @ b*8192, B @ 24576+b*8192
  char* Ub = (char*)U;
  const int tid = threadIdx.x;
  const int wid = tid >> 6, lane = tid & 63;
  const int g = lane >> 4, lq = lane & 15;
  // XCD-chunk swizzle: 1536 blocks = 8 XCDs x 192 contiguous logicals
  const int bx0 = blockIdx.x;
  const int bx = (bx0 & 7) * 192 + (bx0 >> 3);
  const int bm = bx / 24, bn = bx % 24;
  const int brow = bm << 7, bcol = bn << 7;
  const int wr = (wid >> 1) << 6, wc = (wid & 1) << 6;

  // staging: thread handles chunks c0=tid, c1=tid+256 per array (16B each).
  // chunk c -> LDS row c>>2, slot c&3 (linear dest); global source column is
  // inverse-swizzled so read-side slot=(g+(row>>1))&3 recovers K-chunk g.
  const int c0 = tid, c1 = tid + 256;
  const int r0 = c0 >> 2, s0_ = (((c0 & 3) - (r0 >> 1)) & 3) << 4;
  const int r1 = c1 >> 2, s1_ = (((c1 & 3) - (r1 >> 1)) & 3) << 4;
  const char* Ag = (const char*)A;
  const char* Bg = (const char*)Bm;

#define STAGEQ(ko, buf)                                                       \
  {                                                                           \
    gload_lds16(Ag + (size_t)(brow + r0) * 2048 + (ko) + s0_,                 \
                Ub + (buf) * 8192 + c0 * 16);                                 \
    gload_lds16(Ag + (size_t)(brow + r1) * 2048 + (ko) + s1_,                 \
                Ub + (buf) * 8192 + c1 * 16);                                 \
    gload_lds16(Bg + (size_t)(bcol + r0) * 2048 + (ko) + s0_,                 \
                Ub + 24576 + (buf) * 8192 + c0 * 16);                         \
    gload_lds16(Bg + (size_t)(bcol + r1) * 2048 + (ko) + s1_,                 \
                Ub + 24576 + (buf) * 8192 + c1 * 16);                         \
  }

  f32x4 acc[4][4] = {};

  STAGEQ(0, 0); STAGEQ(64, 1);       // prologue: k0,k1 (8 outstanding)
  int cur = 0;
#pragma unroll 1
  for (int t = 0; t < 32; ++t) {
    if (t + 1 < 32) { WAITV4; } else { WAITV0; }  // stage(t) landed
    BARR; SB0;                       // visible to all; buf[(t+2)%3] free
    if (t + 2 < 32) {
      int nb = cur + 2; if (nb >= 3) nb -= 3;
      STAGEQ((t + 2) << 6, nb);
    }
    const char* Ac = Ub + cur * 8192;
    const char* Bc = Ub + 24576 + cur * 8192;
    bf16x8 av[4], bv[4];
#pragma unroll
    for (int m = 0; m < 4; ++m) {
      int row = wr + m * 16 + lq;
      int sl = (g + (row >> 1)) & 3;
      av[m] = *(const bf16x8*)(Ac + row * 64 + sl * 16);
    }
#pragma unroll
    for (int n = 0; n < 4; ++n) {
      int row = wc + n * 16 + lq;
      int sl = (g + (row >> 1)) & 3;
      bv[n] = *(const bf16x8*)(Bc + row * 64 + sl * 16);
    }
#pragma unroll
    for (int m = 0; m < 4; ++m)
#pragma unroll
      for (int n = 0; n < 4; ++n)
        acc[m][n] = __builtin_amdgcn_mfma_f32_16x16x32_bf16(av[m], bv[n], acc[m][n], 0, 0, 0);
    SB0;
    cur = (cur == 2) ? 0 : cur + 1;
  }
#undef STAGEQ

  const int proj = bn >> 3;   // uniform per block (8 x 128 = 1024 cols / proj)
  if (proj < 2) {
    // epilogue: bias + bf16 head-split store [proj][B,H,T,HD]
    const float* bias = proj == 0 ? b0 : b1;
    const float bsc = proj == 0 ? SCQ : 1.f;
#pragma unroll
    for (int n = 0; n < 4; ++n) {
      int col = bcol + wc + n * 16 + lq;
      int cw = col & (CC - 1);
      float bb = bias[cw] * bsc;
      int h_ = cw >> 6, d_ = cw & (HD - 1);
#pragma unroll
      for (int m = 0; m < 4; ++m) {
        int row0 = brow + wr + m * 16 + g * 4;
#pragma unroll
        for (int i = 0; i < 4; ++i) {
          int row = row0 + i;
          int b_ = row >> 11, t_ = row & (TT - 1);
          out[((size_t)proj << 23) +
              ((((size_t)b_ * HH + h_) * TT + t_) << 6) + d_] =
              (__bf16)(acc[m][n][i] + bb);
        }
      }
    }
  } else {
    // V: transpose 128x128 tile through lt (2 chunks of 64 cols = 1 head
    // each) -> Vt[bh][d][t] coalesced. lt ALIASES buffers: barrier first.
    __syncthreads();                             // all K-loop LDS reads done
    __bf16* lt = U;                              // [64 cols][130 rows]
    const int cv0 = (bn & 7) << 7;               // col offset within V region
    const int b_ = brow >> 11, t0 = brow & (TT - 1);
    const int hbase = (bn & 7) << 1;
    const int rd_d = tid >> 2, rd_tb = (tid & 3) << 5;   // 64 d x 128 t
#pragma unroll
    for (int cc = 0; cc < 2; ++cc) {
      if ((wid & 1) == cc) {                     // 2 writer waves per chunk
#pragma unroll
        for (int n = 0; n < 4; ++n) {
          int c = (n << 4) + lq;                 // 0..63 within chunk
          float bb = b2[cv0 + (cc << 6) + c];
#pragma unroll
          for (int m = 0; m < 4; ++m) {
            int r = wr + (m << 4) + (g << 2);    // 0..127 over both writers
            bf16x4 pk;
#pragma unroll
            for (int i = 0; i < 4; ++i)
              pk[i] = (__bf16)(acc[m][n][i] + bb);
            *(bf16x4*)(lt + c * 130 + r) = pk;
          }
        }
      }
      __syncthreads();
      // readers: all 256 threads; d = tid>>2, 32 t-elems each
      __bf16* dst = vt + (((size_t)((b_ * HH + hbase + cc) * HD + rd_d)) << 11)
                       + t0 + rd_tb;
      const __bf16* srcl = lt + rd_d * 130 + rd_tb;
#pragma unroll
      for (int j = 0; j < 4; ++j)
        *(bf16x8*)(dst + j * 8) = *(const bf16x8*)(srcl + j * 8);
      __syncthreads();
    }
  }
}

// ==== proj GEMM v13: same triple-buffered pipeline, fp32 out ================
__global__ __launch_bounds__(256, 2)
void gemm_proj(const __bf16* __restrict__ A, const __bf16* __restrict__ Bm,
               const float* __restrict__ bias, float* __restrict__ out) {
  __shared__ __bf16 U[24576];        // 48KB: A bufs @ b*8192, B @ 24576+b*8192
  char* Ub = (char*)U;
  const int tid = threadIdx.x;
  const int wid = tid >> 6, lane = tid & 63;
  const int g = lane >> 4, lq = lane & 15;
  // XCD-chunk swizzle: 512 blocks = 8 XCDs x 64 contiguous logicals
  const int bx0 = blockIdx.x;
  const int bx = (bx0 & 7) * 64 + (bx0 >> 3);
  const int brow = (bx >> 3) << 7;         // 64 bm
  const int bcol = (bx & 7) << 7;          // 8 bn
  const int wr = (wid >> 1) << 6, wc = (wid & 1) << 6;

  const int c0 = tid, c1 = tid + 256;
  const int r0 = c0 >> 2, s0_ = (((c0 & 3) - (r0 >> 1)) & 3) << 4;
  const int r1 = c1 >> 2, s1_ = (((c1 & 3) - (r1 >> 1)) & 3) << 4;
  const char* Ag = (const char*)A;
  const char* Bg = (const char*)Bm;

#define STAGEP(ko, buf)                                                       \
  {                                                                           \
    gload_lds16(Ag + (size_t)(brow + r0) * 2048 + (ko) + s0_,                 \
                Ub + (buf) * 8192 + c0 * 16);                                 \
    gload_lds16(Ag + (size_t)(brow + r1) * 2048 + (ko) + s1_,                 \
                Ub + (buf) * 8192 + c1 * 16);                                 \
    gload_lds16(Bg + (size_t)(bcol + r0) * 2048 + (ko) + s0_,                 \
                Ub + 24576 + (buf) * 8192 + c0 * 16);                         \
    gload_lds16(Bg + (size_t)(bcol + r1) * 2048 + (ko) + s1_,                 \
                Ub + 24576 + (buf) * 8192 + c1 * 16);                         \
  }

  f32x4 acc[4][4] = {};

  STAGEP(0, 0); STAGEP(64, 1);
  int cur = 0;
#pragma unroll 1
  for (int t = 0; t < 32; ++t) {
    if (t + 1 < 32) { WAITV4; } else { WAITV0; }
    BARR; SB0;
    if (t + 2 < 32) {
      int nb = cur + 2; if (nb >= 3) nb -= 3;
      STAGEP((t + 2) << 6, nb);
    }
    const char* Ac = Ub + cur * 8192;
    const char* Bc = Ub + 24576 + cur * 8192;
    bf16x8 av[4], bv[4];
#pragma unroll
    for (int m = 0; m < 4; ++m) {
      int row = wr + m * 16 + lq;
      int sl = (g + (row >> 1)) & 3;
      av[m] = *(const bf16x8*)(Ac + row * 64 + sl * 16);
    }
#pragma unroll
    for (int n = 0; n < 4; ++n) {
      int row = wc + n * 16 + lq;
      int sl = (g + (row >> 1)) & 3;
      bv[n] = *(const bf16x8*)(Bc + row * 64 + sl * 16);
    }
#pragma unroll
    for (int m = 0; m < 4; ++m)
#pragma unroll
      for (int n = 0; n < 4; ++n)
        acc[m][n] = __builtin_amdgcn_mfma_f32_16x16x32_bf16(av[m], bv[n], acc[m][n], 0, 0, 0);
    SB0;
    cur = (cur == 2) ? 0 : cur + 1;
  }
#undef STAGEP

#pragma unroll
  for (int m = 0; m < 4; ++m) {
#pragma unroll
    for (int n = 0; n < 4; ++n) {
      int col = bcol + wc + n * 16 + lq;
      float bb = bias[col];
      int row0 = brow + wr + m * 16 + g * 4;
#pragma unroll
      for (int i = 0; i < 4; ++i)
        out[(size_t)(row0 + i) * CC + col] = acc[m][n][i] + bb;
    }
  }
}

// ---------------- Flash attention v6 (causal + padding mask) ----------------
// grid 1024 = 16 q-tiles x 64 bh, 256 threads = 4 waves x 32 q-rows (QBLK=128).
// 32x32x16 MFMA, swapped QK^T, split-half S, in-register softmax.
// Full-grid residency: double-buffered K/V (32.8KB LDS) + launch_bounds(256,4)
// -> 4 blocks/CU -> all 1024 blocks co-resident. Heavy-first Latin-square qi
// map balances per-CU work. One barrier per tile, counted staging.
// C/D layout (m74/m101): col = lane&31, row = (r&3) + 8*(r>>2) + 4*(lane>>5).
__global__ __launch_bounds__(256, 4)
void attn_fwd(const __bf16* __restrict__ Q, const __bf16* __restrict__ K,
              const __bf16* __restrict__ Vt, const int* __restrict__ pm,
              __bf16* __restrict__ Y) {
  __shared__ __bf16 Ks[2][64 * 64];   // 16 KiB
  __shared__ __bf16 Vs[2][64 * 64];   // 16 KiB
  __shared__ int flg;
  const int tid = threadIdx.x, wid = tid >> 6, lane = tid & 63;
  const int l31 = lane & 31, hi = lane >> 5;
  const int bx = blockIdx.x;
  const int bh = bx & 63, jj = bx >> 6;          // jj 0..15
  const int qi = 15 - (4 * (jj >> 2) + ((jj + (jj >> 2)) & 3));
  const int b_ = bh >> 4, h_ = bh & 15;
  const __bf16* Qb = Q + (size_t)bh * TT * HD;
  const __bf16* Kb = K + (size_t)bh * TT * HD;
  const __bf16* Vb = Vt + (size_t)bh * HD * TT;
  const int* pmb = pm + b_ * TT;

  const int so = tid * 16;                 // 16B chunk, 0..4080
  const int srow = tid >> 3;               // 0..31
  const int scol = (so & 127) ^ ((srow & 7) << 4);   // inverse-swizzled src col

  const int q0 = qi << 7;
  const int qw = q0 + wid * 32;            // this wave's 32 q-rows
  const int ntiles = 2 * qi + 2;           // >= 2 always
  const int sw0 = (l31 & 7) << 4;

  // Q fragments: lane holds Q[qw+l31][16s + 8hi .. +7], s=0..3
  bf16x8 qf[4];
#pragma unroll
  for (int s = 0; s < 4; ++s)
    qf[s] = *(const bf16x8*)(Qb + (size_t)(qw + l31) * HD + s * 16 + hi * 8);
  SB0;   // pin qf loads above the staging issues (vmcnt accounting)

  // padding-mask block check: 256 threads x 2 int4 cover the 2048-int pm row
  int4 pa4 = ((const int4*)pmb)[tid];
  int4 pb4 = ((const int4*)pmb)[tid + 256];
  bool okp = pa4.x && pa4.y && pa4.z && pa4.w &&
             pb4.x && pb4.y && pb4.z && pb4.w;
  if (tid == 0) flg = 1;
  __syncthreads();
  if (!okp) flg = 0;                       // benign race (all writers store 0)

  // prologue: stage tile 0 into buf 0 (4 gloads: 2 K + 2 V)
  {
    char* kd = (char*)&Ks[0][0] + so;
    char* vd = (char*)&Vs[0][0] + so;
#pragma unroll
    for (int j = 0; j < 2; ++j) {
      gload_lds16((const char*)Kb + (size_t)(srow + 32 * j) * 128 + scol,
                  kd + j * 4096);
      gload_lds16((const char*)Vb + (size_t)(srow + 32 * j) * (TT * 2) + scol,
                  vd + j * 4096);
    }
  }
  __syncthreads();                         // tile 0 staged everywhere; flg final
  const bool allones = (flg != 0);

  f32x16 o0 = {}, o1 = {};                 // O[q=crow(r,hi)][d = l31 | 32+l31]
  f32x16 vzero = {};                       // persistent zero C-operand
  float lsum = 0.f;                        // partial row-sum (this lane-half)
  float m = -INFINITY;                     // running max for q = qw+l31

  int cur = 0;
#pragma unroll 1
  for (int t = 0; t < ntiles; ++t) {
    const int kv0 = t << 6;
    // ---- own stage(t) done (issued a full compute phase ago -> cheap) ----
    WAITV0;
    __builtin_amdgcn_s_barrier(); SB0;  // tile t staged AND t-1 reads done
    // ---- issue stage(t+1) into buf[cur^1] (tile t-1's slot, now free) ----
    if (t + 1 < ntiles) {
      char* kd = (char*)&Ks[0][0] + (cur ^ 1) * 8192 + so;
      char* vd = (char*)&Vs[0][0] + (cur ^ 1) * 8192 + so;
      const size_t nk = (size_t)(kv0 + 64);
#pragma unroll
      for (int j = 0; j < 2; ++j) {
        gload_lds16((const char*)Kb + (nk + srow + 32 * j) * 128 + scol,
                    kd + j * 4096);
        gload_lds16((const char*)Vb + (size_t)(srow + 32 * j) * (TT * 2) +
                        nk * 2 + scol,
                    vd + j * 4096);
      }
    }

    unsigned long long bits = ~0ull;
    if (__builtin_expect(!allones, 0))     // rare slow path
      bits = __ballot(pmb[kv0 + lane] != 0);

    if (kv0 <= qw + 31) {                  // wave-uniform participation
      const char* VsC = (const char*)&Vs[0][0] + cur * 8192;

#pragma unroll
      for (int h = 0; h < 2; ++h) {
        const int kvh = kv0 + 32 * h;
        if (kvh <= qw + 31) {              // wave-uniform per-half gate
          // ---- QK^T (swapped): S[kvh+crow][q=l31] ----
          const char* KsC =
              (const char*)&Ks[0][0] + cur * 8192 + (32 * h + l31) * 128;
          f32x16 S;
          __builtin_amdgcn_s_setprio(1);
          {
            bf16x8 k0 = *(const bf16x8*)(KsC + ((16 * hi) ^ sw0));
            S = __builtin_amdgcn_mfma_f32_32x32x16_bf16(k0, qf[0], vzero, 0, 0, 0);
          }
#pragma unroll
          for (int s = 1; s < 4; ++s) {
            bf16x8 kf = *(const bf16x8*)(KsC + ((32 * s + 16 * hi) ^ sw0));
            S = __builtin_amdgcn_mfma_f32_32x32x16_bf16(kf, qf[s], S, 0, 0, 0);
          }
          __builtin_amdgcn_s_setprio(0);

          // ---- masks ----
          if (__builtin_expect(bits != ~0ull, 0)) {   // padding (rare)
#pragma unroll
            for (int r = 0; r < 16; ++r) {
              const int c = (r & 3) + 8 * (r >> 2);
              if (!((bits >> (32 * h + c + 4 * hi)) & 1ull)) S[r] = -INFINITY;
            }
          }
          if (kvh + 31 > qw) {             // causal diag (wave-uniform)
            const int thr = qw + l31 - kvh - 4 * hi;
#pragma unroll
            for (int r = 0; r < 16; ++r) {
              const int c = (r & 3) + 8 * (r >> 2);
              S[r] = (c <= thr) ? S[r] : -INFINITY;
            }
          }

          // ---- row max via packed-f32 tree + defer-rescale check ----
          f32x2 x0 = {S[0], S[1]},  x1 = {S[2], S[3]};
          f32x2 x2 = {S[4], S[5]},  x3 = {S[6], S[7]};
          f32x2 x4 = {S[8], S[9]},  x5 = {S[10], S[11]};
          f32x2 x6 = {S[12], S[13]}, x7 = {S[14], S[15]};
          x0 = max2(x0, x4); x1 = max2(x1, x5);
          x2 = max2(x2, x6); x3 = max2(x3, x7);
          x0 = max2(x0, x2); x1 = max2(x1, x3);
          x0 = max2(x0, x1);
          float pmax = fmaxf(x0[0], x0[1]);
          if (!__all(pmax <= m + 8.f)) {
            float nm = fmaxf(pmax, __shfl_xor(pmax, 32));  // full row max
            float mn = fmaxf(m, nm);
            float c = fast_exp2(m - mn);
            m = mn;
            lsum *= c;
#pragma unroll
            for (int r = 0; r < 16; ++r) {
              float cr = __shfl(c, (r & 3) + 8 * (r >> 2) + 4 * hi);
              o0[r] *= cr;
              o1[r] *= cr;
            }
          }

          // ---- P = exp2(S - m) (packed sub, trans exp) ----
          const f32x2 mm = {m, m};
#pragma unroll
          for (int r = 0; r < 16; r += 2) {
            f32x2 u = {S[r], S[r + 1]};
            u -= mm;                      // v_pk_add_f32
            S[r] = fast_exp2(u[0]);
            S[r + 1] = fast_exp2(u[1]);
          }
          // ---- in-lane row-sum via packed-f32 tree ----
          {
            f32x2 u0 = {S[0], S[1]},  u1 = {S[2], S[3]};
            f32x2 u2 = {S[4], S[5]},  u3 = {S[6], S[7]};
            f32x2 u4 = {S[8], S[9]},  u5 = {S[10], S[11]};
            f32x2 u6 = {S[12], S[13]}, u7 = {S[14], S[15]};
            u0 += u4; u1 += u5; u2 += u6; u3 += u7;
            u0 += u2; u1 += u3;
            u0 += u1;
            lsum += u0[0] + u0[1];
          }

          // ---- PV: build A-fragments (validated select+shfl_xor exchange) ----
          __builtin_amdgcn_s_setprio(1);
#pragma unroll
          for (int s = 0; s < 2; ++s) {
            int A0 = cvt_pk_bf16(S[8 * s + 0], S[8 * s + 1]);
            int A1 = cvt_pk_bf16(S[8 * s + 2], S[8 * s + 3]);
            int B0 = cvt_pk_bf16(S[8 * s + 4], S[8 * s + 5]);
            int B1 = cvt_pk_bf16(S[8 * s + 6], S[8 * s + 7]);
            // exchange across lane+-32: lo lanes need A-pairs of BOTH halves,
            // hi lanes need B-pairs of BOTH halves.
            int s0 = hi ? A0 : B0, s1 = hi ? A1 : B1;
            int e0 = __shfl_xor(s0, 32), e1 = __shfl_xor(s1, 32);
            i32x4 wv;
            wv[0] = hi ? e0 : A0;
            wv[1] = hi ? e1 : A1;
            wv[2] = hi ? B0 : e0;
            wv[3] = hi ? B1 : e1;
            bf16x8 pa = __builtin_bit_cast(bf16x8, wv);
            const int co = 64 * h + 32 * s + 16 * hi;   // kv byte offset
            bf16x8 v0 = *(const bf16x8*)(VsC + l31 * 128 + (co ^ sw0));
            bf16x8 v1 = *(const bf16x8*)(VsC + (32 + l31) * 128 + (co ^ sw0));
            o0 = __builtin_amdgcn_mfma_f32_32x32x16_bf16(pa, v0, o0, 0, 0, 0);
            o1 = __builtin_amdgcn_mfma_f32_32x32x16_bf16(pa, v1, o1, 0, 0, 0);
          }
          __builtin_amdgcn_s_setprio(0);
        }
      }
    }
    SB0;   // pin this tile's LDS reads above next iteration's barrier
    cur ^= 1;
  }

  // epilogue: combine lane-halves' row-sums, normalize + store
  float linv = 1.f / (lsum + __shfl_xor(lsum, 32));
#pragma unroll
  for (int r = 0; r < 16; ++r) {
    const int crow = (r & 3) + 8 * (r >> 2) + 4 * hi;
    float ir = __shfl(linv, crow);
    const int qrow = qw + crow;
    __bf16* yp = Y + ((size_t)(b_ * TT + qrow)) * CC + h_ * HD + l31;
    yp[0]  = (__bf16)(o0[r] * ir);
    yp[32] = (__bf16)(o1[r] * ir);
  }
}

// ---------------- launch ----------------
extern "C" void kernel_launch(void* const* d_in, const int* in_sizes, int n_in,
                              void* d_out, int out_size, void* d_ws, size_t ws_size,
                              hipStream_t stream) {
  (void)in_sizes; (void)n_in; (void)out_size; (void)ws_size;
  const float* x  = (const float*)d_in[0];
  const float* Wk = (const float*)d_in[1];
  const float* bk = (const float*)d_in[2];
  const float* Wq = (const float*)d_in[3];
  const float* bq = (const float*)d_in[4];
  const float* Wv = (const float*)d_in[5];
  const float* bv = (const float*)d_in[6];
  const float* Wp = (const float*)d_in[7];
  const float* bp = (const float*)d_in[8];
  const int* pmask = (const int*)d_in[9];

  char* ws = (char*)d_ws;
  const size_t MB = 1024 * 1024;
  __bf16* xb   = (__bf16*)(ws);            // 16MB; reused as attn-out y
  __bf16* wqkv = (__bf16*)(ws + 16 * MB);  // 6MB  [3072][1024] (q,k,v concat)
  __bf16* wpb  = (__bf16*)(ws + 22 * MB);  // 2MB
  __bf16* qb   = (__bf16*)(ws + 24 * MB);  // 16MB [B,H,T,HD]
  __bf16* kb   = qb + ((size_t)1 << 23);   // 16MB @40MB
  __bf16* vtb  = (__bf16*)(ws + 56 * MB);  // 16MB [B,H,HD,T] (written by gemm_qkv)
  __bf16* yb   = xb;                       // attn out overwrites x

  int n4 = (MM * CC) / 4;                  // 2097152
  cvt_f32_bf16<<<(n4 + 255) / 256, 256, 0, stream>>>(x, xb, n4);
  cvt_w4<<<dim3((CC * CC / 4) / 256, 4), 256, 0, stream>>>(
      Wq, Wk, Wv, Wp, wqkv, wpb);

  // fused QKV projection + V-transpose epilogue (128x128 tiles, grid 1536)
  gemm_qkv<<<(MM / 128) * (3 * CC / 128), 256, 0, stream>>>(
      xb, wqkv, bq, bk, bv, qb, vtb);

  attn_fwd<<<NQT2 * BB * HH, 256, 0, stream>>>(qb, kb, vtb, pmask, yb);

  gemm_proj<<<(MM / 128) * (CC / 128), 256, 0, stream>>>(
      yb, wpb, bp, (float*)d_out);
}